// Round 1
// baseline (4397.408 us; speedup 1.0000x reference)
//
#include <hip/hip_runtime.h>
#include <math.h>

constexpr int B_  = 16384;   // batch
constexpr int DIN = 1024;    // input dim
constexpr int DH  = 2048;    // hidden dim
constexpr int DL  = 256;     // latent dim
constexpr int NE  = 8192;    // codebook entries

// ---------------------------------------------------------------------------
// Tiled fp32 GEMM: C = epi(A @ B + bias)
// A [M,K] row-major, B [K,N] row-major, bias [N].
// 128x128 tile, BK=8, 256 threads, 8x8 micro-tile per thread.
// EPI: 0 = bias only, 1 = relu, 2 = sigmoid
// M % 128 == 0, N % 128 == 0, K % 8 == 0 (all shapes here satisfy this).
// ---------------------------------------------------------------------------
template <int EPI>
__global__ __launch_bounds__(256)
void gemm_f32(const float* __restrict__ A, const float* __restrict__ Bm,
              const float* __restrict__ bias, float* __restrict__ C,
              int M, int N, int K)
{
    constexpr int BM = 128, BN = 128, BK = 8;
    __shared__ float As[BK][BM];   // A tile, transposed
    __shared__ float Bs[BK][BN];

    const int tid = threadIdx.x;
    const int tx  = tid & 15;      // 16 threads along N, 8 cols each
    const int ty  = tid >> 4;      // 16 threads along M, 8 rows each
    const long bx = blockIdx.x;    // N tile
    const long by = blockIdx.y;    // M tile

    // global-load mapping
    const int a_row = tid >> 1;            // 0..127
    const int a_col = (tid & 1) * 4;       // 0 or 4
    const int b_row = tid >> 5;            // 0..7
    const int b_col = (tid & 31) * 4;      // 0..124

    const float* Ap = A + (by * BM + a_row) * (long)K + a_col;
    const float* Bp = Bm + (long)b_row * N + bx * BN + b_col;

    float acc[8][8];
#pragma unroll
    for (int i = 0; i < 8; ++i)
#pragma unroll
        for (int j = 0; j < 8; ++j) acc[i][j] = 0.f;

    for (int k0 = 0; k0 < K; k0 += BK) {
        float4 av = *(const float4*)(Ap + k0);
        float4 bv = *(const float4*)(Bp + (long)k0 * N);
        As[a_col + 0][a_row] = av.x;
        As[a_col + 1][a_row] = av.y;
        As[a_col + 2][a_row] = av.z;
        As[a_col + 3][a_row] = av.w;
        *(float4*)&Bs[b_row][b_col] = bv;
        __syncthreads();

#pragma unroll
        for (int k = 0; k < BK; ++k) {
            float4 a0 = *(const float4*)&As[k][ty * 8];
            float4 a1 = *(const float4*)&As[k][ty * 8 + 4];
            float4 b0 = *(const float4*)&Bs[k][tx * 8];
            float4 b1 = *(const float4*)&Bs[k][tx * 8 + 4];
            float af[8] = {a0.x, a0.y, a0.z, a0.w, a1.x, a1.y, a1.z, a1.w};
            float bf[8] = {b0.x, b0.y, b0.z, b0.w, b1.x, b1.y, b1.z, b1.w};
#pragma unroll
            for (int i = 0; i < 8; ++i)
#pragma unroll
                for (int j = 0; j < 8; ++j)
                    acc[i][j] = fmaf(af[i], bf[j], acc[i][j]);
        }
        __syncthreads();
    }

    const long crow = by * BM + ty * 8;
    const long ccol = bx * BN + tx * 8;
    float bb[8];
#pragma unroll
    for (int j = 0; j < 8; ++j) bb[j] = bias[ccol + j];

#pragma unroll
    for (int i = 0; i < 8; ++i) {
#pragma unroll
        for (int j0 = 0; j0 < 8; j0 += 4) {
            float4 v;
            float e0 = acc[i][j0 + 0] + bb[j0 + 0];
            float e1 = acc[i][j0 + 1] + bb[j0 + 1];
            float e2 = acc[i][j0 + 2] + bb[j0 + 2];
            float e3 = acc[i][j0 + 3] + bb[j0 + 3];
            if (EPI == 1) {
                e0 = fmaxf(e0, 0.f); e1 = fmaxf(e1, 0.f);
                e2 = fmaxf(e2, 0.f); e3 = fmaxf(e3, 0.f);
            }
            if (EPI == 2) {
                e0 = 1.f / (1.f + expf(-e0));
                e1 = 1.f / (1.f + expf(-e1));
                e2 = 1.f / (1.f + expf(-e2));
                e3 = 1.f / (1.f + expf(-e3));
            }
            v.x = e0; v.y = e1; v.z = e2; v.w = e3;
            *(float4*)&C[(crow + i) * (long)N + ccol + j0] = v;
        }
    }
}

// ---------------------------------------------------------------------------
// cn2[k] = 0.5 * ||codebook[k]||^2.  One wave per code (64 lanes * 4 floats).
// ---------------------------------------------------------------------------
__global__ __launch_bounds__(256)
void cn2_kernel(const float* __restrict__ cb, float* __restrict__ cn2)
{
    const int code = (blockIdx.x * 256 + threadIdx.x) >> 6;
    const int lane = threadIdx.x & 63;
    float4 v = *(const float4*)(cb + (long)code * DL + lane * 4);
    float s = fmaf(v.x, v.x, fmaf(v.y, v.y, fmaf(v.z, v.z, v.w * v.w)));
#pragma unroll
    for (int off = 32; off; off >>= 1) s += __shfl_down(s, off);
    if (lane == 0) cn2[code] = 0.5f * s;
}

// ---------------------------------------------------------------------------
// Fused VQ: per 32-row tile, scan all 8192 codes.
//   score(n,k) = 0.5*||c_k||^2 - z_n . c_k   (same argmin as full distance)
// Running per-thread best (2 rows x 16 codes per thread), shuffle-reduce
// across the 16 code-lanes, then gather z_q rows, accumulate
// sum((z_q - z)^2) per block into partial[] (deterministic, no atomics).
// Tie-break: lowest code index (matches jnp.argmin), codes scanned ascending.
// ---------------------------------------------------------------------------
__global__ __launch_bounds__(256)
void vq_argmin(const float* __restrict__ z, const float* __restrict__ cb,
               const float* __restrict__ cn2, float* __restrict__ zq,
               float* __restrict__ partial)
{
    constexpr int BM = 32, CN = 256, BK = 8;
    __shared__ float Zs[BK][BM];
    __shared__ float Cs[BK][CN];
    __shared__ int   s_idx[BM];
    __shared__ float s_red[4];

    const int tid = threadIdx.x;
    const int tx  = tid & 15;   // 16 threads -> 16 codes each (contiguous)
    const int ty  = tid >> 4;   // 16 groups -> 2 rows each
    const long by = blockIdx.x;

    const int zr = tid >> 1, zc = (tid & 1) * 4;  // tid<64 loads Z tile
    const int cr = tid >> 1, cc = (tid & 1) * 4;  // 2 passes of 128 code rows

    float best_val[2] = {1e30f, 1e30f};
    int   best_idx[2] = {0, 0};

    const float* zbase = z + by * BM * (long)DL;

    for (int ch = 0; ch < NE / CN; ++ch) {
        float acc[2][16];
#pragma unroll
        for (int i = 0; i < 2; ++i)
#pragma unroll
            for (int j = 0; j < 16; ++j) acc[i][j] = 0.f;

        const float* cbase = cb + (long)ch * CN * DL;

        for (int k0 = 0; k0 < DL; k0 += BK) {
            if (tid < 64) {
                float4 v = *(const float4*)(zbase + (long)zr * DL + k0 + zc);
                Zs[zc + 0][zr] = v.x; Zs[zc + 1][zr] = v.y;
                Zs[zc + 2][zr] = v.z; Zs[zc + 3][zr] = v.w;
            }
#pragma unroll
            for (int p = 0; p < 2; ++p) {
                const int row = p * 128 + cr;
                float4 v = *(const float4*)(cbase + (long)row * DL + k0 + cc);
                Cs[cc + 0][row] = v.x; Cs[cc + 1][row] = v.y;
                Cs[cc + 2][row] = v.z; Cs[cc + 3][row] = v.w;
            }
            __syncthreads();

#pragma unroll
            for (int k = 0; k < BK; ++k) {
                float2 zv = *(const float2*)&Zs[k][ty * 2];
                float zf[2] = {zv.x, zv.y};
                float4 c0 = *(const float4*)&Cs[k][tx * 16 + 0];
                float4 c1 = *(const float4*)&Cs[k][tx * 16 + 4];
                float4 c2 = *(const float4*)&Cs[k][tx * 16 + 8];
                float4 c3 = *(const float4*)&Cs[k][tx * 16 + 12];
                float cf[16] = {c0.x, c0.y, c0.z, c0.w, c1.x, c1.y, c1.z, c1.w,
                                c2.x, c2.y, c2.z, c2.w, c3.x, c3.y, c3.z, c3.w};
#pragma unroll
                for (int i = 0; i < 2; ++i)
#pragma unroll
                    for (int j = 0; j < 16; ++j)
                        acc[i][j] = fmaf(zf[i], cf[j], acc[i][j]);
            }
            __syncthreads();
        }

#pragma unroll
        for (int j = 0; j < 16; ++j) {
            const int code = ch * CN + tx * 16 + j;
            const float hc2 = cn2[code];
#pragma unroll
            for (int i = 0; i < 2; ++i) {
                const float score = hc2 - acc[i][j];
                if (score < best_val[i]) { best_val[i] = score; best_idx[i] = code; }
            }
        }
    }

    // reduce across the 16 code-lanes (same ty group = 16 consecutive lanes)
#pragma unroll
    for (int off = 1; off < 16; off <<= 1) {
#pragma unroll
        for (int i = 0; i < 2; ++i) {
            float ov = __shfl_xor(best_val[i], off);
            int   oi = __shfl_xor(best_idx[i], off);
            if (ov < best_val[i] || (ov == best_val[i] && oi < best_idx[i])) {
                best_val[i] = ov; best_idx[i] = oi;
            }
        }
    }
    if (tx == 0) { s_idx[ty * 2] = best_idx[0]; s_idx[ty * 2 + 1] = best_idx[1]; }
    __syncthreads();

    // phase 2: gather z_q rows + loss partial. 8 threads per row, 32 dims each.
    const int row = tid >> 3, sub = tid & 7;
    const int gi  = s_idx[row];
    const float* crow = cb + (long)gi * DL;
    const float* zrow = zbase + (long)row * DL;
    float* qrow = zq + (by * BM + row) * (long)DL;
    float ls = 0.f;
#pragma unroll
    for (int t = 0; t < 8; ++t) {
        const int d = sub * 4 + t * 32;
        float4 c4 = *(const float4*)(crow + d);
        float4 z4 = *(const float4*)(zrow + d);
        const float dx = c4.x - z4.x, dy = c4.y - z4.y;
        const float dz = c4.z - z4.z, dw = c4.w - z4.w;
        ls += dx * dx + dy * dy + dz * dz + dw * dw;
        *(float4*)(qrow + d) = c4;
    }
#pragma unroll
    for (int off = 32; off; off >>= 1) ls += __shfl_down(ls, off);
    if ((tid & 63) == 0) s_red[tid >> 6] = ls;
    __syncthreads();
    if (tid == 0) partial[by] = s_red[0] + s_red[1] + s_red[2] + s_red[3];
}

// ---------------------------------------------------------------------------
// loss = 1.25 * sum(partial) / (B_*DL)   (vq_loss + commitment, forward value)
// ---------------------------------------------------------------------------
__global__ __launch_bounds__(256)
void loss_finalize(const float* __restrict__ partial, float* __restrict__ out)
{
    __shared__ float s_red[4];
    const int tid = threadIdx.x;
    float s = partial[tid] + partial[tid + 256];   // 512 partials
#pragma unroll
    for (int off = 32; off; off >>= 1) s += __shfl_down(s, off);
    if ((tid & 63) == 0) s_red[tid >> 6] = s;
    __syncthreads();
    if (tid == 0)
        out[0] = 1.25f * (s_red[0] + s_red[1] + s_red[2] + s_red[3])
                 / (float)((long)B_ * DL);
}

// ---------------------------------------------------------------------------
extern "C" void kernel_launch(void* const* d_in, const int* in_sizes, int n_in,
                              void* d_out, int out_size, void* d_ws, size_t ws_size,
                              hipStream_t stream)
{
    const float* x   = (const float*)d_in[0];
    const float* ew1 = (const float*)d_in[1];
    const float* eb1 = (const float*)d_in[2];
    const float* ew2 = (const float*)d_in[3];
    const float* eb2 = (const float*)d_in[4];
    const float* cbk = (const float*)d_in[5];
    const float* dw1 = (const float*)d_in[6];
    const float* db1 = (const float*)d_in[7];
    const float* dw2 = (const float*)d_in[8];
    const float* db2 = (const float*)d_in[9];
    float* out = (float*)d_out;

    float* ws   = (float*)d_ws;
    float* h    = ws;                          // [B_, DH]   (reused for decoder hidden)
    float* z    = h  + (size_t)B_ * DH;        // [B_, DL]
    float* zq   = z  + (size_t)B_ * DL;        // [B_, DL]
    float* cn2  = zq + (size_t)B_ * DL;        // [NE]
    float* part = cn2 + NE;                    // [512]

    // 0.5*||c||^2 per code
    cn2_kernel<<<NE / 4, 256, 0, stream>>>(cbk, cn2);

    // encoder
    gemm_f32<1><<<dim3(DH / 128, B_ / 128), 256, 0, stream>>>(x, ew1, eb1, h, B_, DH, DIN);
    gemm_f32<0><<<dim3(DL / 128, B_ / 128), 256, 0, stream>>>(h, ew2, eb2, z, B_, DL, DH);

    // vector quantizer (argmin + gather + loss partials)
    vq_argmin<<<B_ / 32, 256, 0, stream>>>(z, cbk, cn2, zq, part);
    loss_finalize<<<1, 256, 0, stream>>>(part, out + (size_t)B_ * DIN);

    // decoder
    gemm_f32<1><<<dim3(DH / 128, B_ / 128), 256, 0, stream>>>(zq, dw1, db1, h, B_, DH, DL);
    gemm_f32<2><<<dim3(DIN / 128, B_ / 128), 256, 0, stream>>>(h, dw2, db2, out, B_, DIN, DH);
}

// Round 3
// 2830.395 us; speedup vs baseline: 1.5536x; 1.5536x over previous
//
#include <hip/hip_runtime.h>
#include <math.h>

constexpr int B_  = 16384;   // batch
constexpr int DIN = 1024;    // input dim
constexpr int DH  = 2048;    // hidden dim
constexpr int DL  = 256;     // latent dim
constexpr int NE  = 8192;    // codebook entries

// ---------------------------------------------------------------------------
// Tiled fp32 GEMM: C = epi(A @ B + bias)
// A [M,K] row-major, B [K,N] row-major, bias [N].
// 128x128 tile, BK=8, 256 threads, 8x8 micro-tile per thread.
// EPI: 0 = bias only, 1 = relu, 2 = sigmoid
// ---------------------------------------------------------------------------
template <int EPI>
__global__ __launch_bounds__(256)
void gemm_f32(const float* __restrict__ A, const float* __restrict__ Bm,
              const float* __restrict__ bias, float* __restrict__ C,
              int M, int N, int K)
{
    constexpr int BM = 128, BN = 128, BK = 8;
    __shared__ float As[BK][BM];   // A tile, transposed
    __shared__ float Bs[BK][BN];

    const int tid = threadIdx.x;
    const int tx  = tid & 15;      // 16 threads along N, 8 cols each
    const int ty  = tid >> 4;      // 16 threads along M, 8 rows each
    const long bx = blockIdx.x;    // N tile
    const long by = blockIdx.y;    // M tile

    const int a_row = tid >> 1;            // 0..127
    const int a_col = (tid & 1) * 4;       // 0 or 4
    const int b_row = tid >> 5;            // 0..7
    const int b_col = (tid & 31) * 4;      // 0..124

    const float* Ap = A + (by * BM + a_row) * (long)K + a_col;
    const float* Bp = Bm + (long)b_row * N + bx * BN + b_col;

    float acc[8][8];
#pragma unroll
    for (int i = 0; i < 8; ++i)
#pragma unroll
        for (int j = 0; j < 8; ++j) acc[i][j] = 0.f;

    for (int k0 = 0; k0 < K; k0 += BK) {
        float4 av = *(const float4*)(Ap + k0);
        float4 bv = *(const float4*)(Bp + (long)k0 * N);
        As[a_col + 0][a_row] = av.x;
        As[a_col + 1][a_row] = av.y;
        As[a_col + 2][a_row] = av.z;
        As[a_col + 3][a_row] = av.w;
        *(float4*)&Bs[b_row][b_col] = bv;
        __syncthreads();

#pragma unroll
        for (int k = 0; k < BK; ++k) {
            float4 a0 = *(const float4*)&As[k][ty * 8];
            float4 a1 = *(const float4*)&As[k][ty * 8 + 4];
            float4 b0 = *(const float4*)&Bs[k][tx * 8];
            float4 b1 = *(const float4*)&Bs[k][tx * 8 + 4];
            float af[8] = {a0.x, a0.y, a0.z, a0.w, a1.x, a1.y, a1.z, a1.w};
            float bf[8] = {b0.x, b0.y, b0.z, b0.w, b1.x, b1.y, b1.z, b1.w};
#pragma unroll
            for (int i = 0; i < 8; ++i)
#pragma unroll
                for (int j = 0; j < 8; ++j)
                    acc[i][j] = fmaf(af[i], bf[j], acc[i][j]);
        }
        __syncthreads();
    }

    const long crow = by * BM + ty * 8;
    const long ccol = bx * BN + tx * 8;
    float bb[8];
#pragma unroll
    for (int j = 0; j < 8; ++j) bb[j] = bias[ccol + j];

#pragma unroll
    for (int i = 0; i < 8; ++i) {
#pragma unroll
        for (int j0 = 0; j0 < 8; j0 += 4) {
            float4 v;
            float e0 = acc[i][j0 + 0] + bb[j0 + 0];
            float e1 = acc[i][j0 + 1] + bb[j0 + 1];
            float e2 = acc[i][j0 + 2] + bb[j0 + 2];
            float e3 = acc[i][j0 + 3] + bb[j0 + 3];
            if (EPI == 1) {
                e0 = fmaxf(e0, 0.f); e1 = fmaxf(e1, 0.f);
                e2 = fmaxf(e2, 0.f); e3 = fmaxf(e3, 0.f);
            }
            if (EPI == 2) {
                e0 = 1.f / (1.f + expf(-e0));
                e1 = 1.f / (1.f + expf(-e1));
                e2 = 1.f / (1.f + expf(-e2));
                e3 = 1.f / (1.f + expf(-e3));
            }
            v.x = e0; v.y = e1; v.z = e2; v.w = e3;
            *(float4*)&C[(crow + i) * (long)N + ccol + j0] = v;
        }
    }
}

// ---------------------------------------------------------------------------
// cn2[k] = 0.5 * ||codebook[k]||^2.  One wave per code.
// ---------------------------------------------------------------------------
__global__ __launch_bounds__(256)
void cn2_kernel(const float* __restrict__ cb, float* __restrict__ cn2)
{
    const int code = (blockIdx.x * 256 + threadIdx.x) >> 6;
    const int lane = threadIdx.x & 63;
    float4 v = *(const float4*)(cb + (long)code * DL + lane * 4);
    float s = fmaf(v.x, v.x, fmaf(v.y, v.y, fmaf(v.z, v.z, v.w * v.w)));
#pragma unroll
    for (int off = 32; off; off >>= 1) s += __shfl_down(s, off);
    if (lane == 0) cn2[code] = 0.5f * s;
}

// ---------------------------------------------------------------------------
// VQ phase 1: GEMM-structured score + within-tile argmin.
// score(n,k) = 0.5*||c_k||^2 - z_n . c_k  (same argmin as full distance).
// One block = 128 rows x 128 codes x K=256, 8x8 micro-tile (identical FMA
// structure + accumulation order as gemm_f32, so scores are bitwise equal
// to the round-1 kernel). Epilogue: per-row argmin over the tile's 128
// codes (tie-break lowest index), written to bval/bidx[row][col_tile].
// Both z [M,256] and cb [N,256] are row-major over K -> symmetric loads.
// ---------------------------------------------------------------------------
__global__ __launch_bounds__(256)
void vq_score(const float* __restrict__ z, const float* __restrict__ cb,
              const float* __restrict__ cn2,
              float* __restrict__ bval, int* __restrict__ bidx)
{
    constexpr int BM = 128, BN = 128, BK = 8;
    __shared__ float Zs[BK][BM];
    __shared__ float Cs[BK][BN];

    const int tid = threadIdx.x;
    const int tx  = tid & 15;
    const int ty  = tid >> 4;
    const long bx = blockIdx.x;    // code tile
    const long by = blockIdx.y;    // row tile

    const int a_row = tid >> 1;
    const int a_col = (tid & 1) * 4;

    const float* Zp = z  + (by * BM + a_row) * (long)DL + a_col;
    const float* Cp = cb + (bx * BN + a_row) * (long)DL + a_col;

    float acc[8][8];
#pragma unroll
    for (int i = 0; i < 8; ++i)
#pragma unroll
        for (int j = 0; j < 8; ++j) acc[i][j] = 0.f;

    for (int k0 = 0; k0 < DL; k0 += BK) {
        float4 av = *(const float4*)(Zp + k0);
        float4 cv = *(const float4*)(Cp + k0);
        Zs[a_col + 0][a_row] = av.x;
        Zs[a_col + 1][a_row] = av.y;
        Zs[a_col + 2][a_row] = av.z;
        Zs[a_col + 3][a_row] = av.w;
        Cs[a_col + 0][a_row] = cv.x;
        Cs[a_col + 1][a_row] = cv.y;
        Cs[a_col + 2][a_row] = cv.z;
        Cs[a_col + 3][a_row] = cv.w;
        __syncthreads();

#pragma unroll
        for (int k = 0; k < BK; ++k) {
            float4 a0 = *(const float4*)&Zs[k][ty * 8];
            float4 a1 = *(const float4*)&Zs[k][ty * 8 + 4];
            float4 b0 = *(const float4*)&Cs[k][tx * 8];
            float4 b1 = *(const float4*)&Cs[k][tx * 8 + 4];
            float af[8] = {a0.x, a0.y, a0.z, a0.w, a1.x, a1.y, a1.z, a1.w};
            float bf[8] = {b0.x, b0.y, b0.z, b0.w, b1.x, b1.y, b1.z, b1.w};
#pragma unroll
            for (int i = 0; i < 8; ++i)
#pragma unroll
                for (int j = 0; j < 8; ++j)
                    acc[i][j] = fmaf(af[i], bf[j], acc[i][j]);
        }
        __syncthreads();
    }

    // per-thread argmin over its 8 codes, for each of its 8 rows
    const int code0 = (int)bx * BN + tx * 8;
    float hc2[8];
#pragma unroll
    for (int j = 0; j < 8; ++j) hc2[j] = cn2[code0 + j];

    float bv_[8];
    int   bi_[8];
#pragma unroll
    for (int i = 0; i < 8; ++i) {
        float b = 1e30f; int bi = 0;
#pragma unroll
        for (int j = 0; j < 8; ++j) {
            const float s = hc2[j] - acc[i][j];
            if (s < b) { b = s; bi = code0 + j; }
        }
        bv_[i] = b; bi_[i] = bi;
    }

    // reduce across the 16 tx-lanes (consecutive lanes within the wave)
#pragma unroll
    for (int off = 1; off < 16; off <<= 1) {
#pragma unroll
        for (int i = 0; i < 8; ++i) {
            float ov = __shfl_xor(bv_[i], off);
            int   oi = __shfl_xor(bi_[i], off);
            if (ov < bv_[i] || (ov == bv_[i] && oi < bi_[i])) {
                bv_[i] = ov; bi_[i] = oi;
            }
        }
    }

    if (tx == 0) {
#pragma unroll
        for (int i = 0; i < 8; ++i) {
            const long row = by * BM + ty * 8 + i;
            bval[row * (NE / BN) + bx] = bv_[i];
            bidx[row * (NE / BN) + bx] = bi_[i];
        }
    }
}

// ---------------------------------------------------------------------------
// VQ phase 2: per row, reduce the 64 column-tile candidates (tie-break
// lowest code index), gather z_q row, accumulate loss partial per block.
// One wave per row; 4 rows per block.
// ---------------------------------------------------------------------------
__global__ __launch_bounds__(256)
void vq_select(const float* __restrict__ bval, const int* __restrict__ bidx,
               const float* __restrict__ z, const float* __restrict__ cb,
               float* __restrict__ zq, float* __restrict__ partial)
{
    __shared__ float s_red[4];
    const int tid  = threadIdx.x;
    const int w    = tid >> 6;
    const int lane = tid & 63;
    const long row = blockIdx.x * 4 + w;

    float v = bval[row * 64 + lane];
    int   i = bidx[row * 64 + lane];
#pragma unroll
    for (int off = 1; off < 64; off <<= 1) {
        float ov = __shfl_xor(v, off);
        int   oi = __shfl_xor(i, off);
        if (ov < v || (ov == v && oi < i)) { v = ov; i = oi; }
    }

    float4 c4 = *(const float4*)(cb + (long)i * DL + lane * 4);
    float4 z4 = *(const float4*)(z + row * (long)DL + lane * 4);
    *(float4*)(zq + row * (long)DL + lane * 4) = c4;
    const float dx = c4.x - z4.x, dy = c4.y - z4.y;
    const float dz = c4.z - z4.z, dw = c4.w - z4.w;
    float ls = dx * dx + dy * dy + dz * dz + dw * dw;
#pragma unroll
    for (int off = 32; off; off >>= 1) ls += __shfl_down(ls, off);
    if (lane == 0) s_red[w] = ls;
    __syncthreads();
    if (tid == 0)
        partial[blockIdx.x] = s_red[0] + s_red[1] + s_red[2] + s_red[3];
}

// ---------------------------------------------------------------------------
// loss = 1.25 * sum(partial[4096]) / (B_*DL)
// ---------------------------------------------------------------------------
__global__ __launch_bounds__(256)
void loss_finalize(const float* __restrict__ partial, float* __restrict__ out)
{
    __shared__ float s_red[4];
    const int tid = threadIdx.x;
    float s = 0.f;
#pragma unroll
    for (int t = 0; t < 16; ++t) s += partial[tid + t * 256];
#pragma unroll
    for (int off = 32; off; off >>= 1) s += __shfl_down(s, off);
    if ((tid & 63) == 0) s_red[tid >> 6] = s;
    __syncthreads();
    if (tid == 0)
        out[0] = 1.25f * (s_red[0] + s_red[1] + s_red[2] + s_red[3])
                 / (float)((long)B_ * DL);
}

// ---------------------------------------------------------------------------
extern "C" void kernel_launch(void* const* d_in, const int* in_sizes, int n_in,
                              void* d_out, int out_size, void* d_ws, size_t ws_size,
                              hipStream_t stream)
{
    const float* x   = (const float*)d_in[0];
    const float* ew1 = (const float*)d_in[1];
    const float* eb1 = (const float*)d_in[2];
    const float* ew2 = (const float*)d_in[3];
    const float* eb2 = (const float*)d_in[4];
    const float* cbk = (const float*)d_in[5];
    const float* dw1 = (const float*)d_in[6];
    const float* db1 = (const float*)d_in[7];
    const float* dw2 = (const float*)d_in[8];
    const float* db2 = (const float*)d_in[9];
    float* out = (float*)d_out;

    float* ws   = (float*)d_ws;
    float* h    = ws;                          // [B_, DH]  (also decoder hidden)
    float* z    = h  + (size_t)B_ * DH;        // [B_, DL]
    float* zq   = z  + (size_t)B_ * DL;        // [B_, DL]
    float* cn2  = zq + (size_t)B_ * DL;        // [NE]
    float* part = cn2 + NE;                    // [4096]
    // (val,idx) candidates overlay h: h is dead between encoder and decoder
    float* bval = h;                           // [B_, 64]
    int*   bidx = (int*)(h + (size_t)B_ * 64); // [B_, 64]

    cn2_kernel<<<NE / 4, 256, 0, stream>>>(cbk, cn2);

    // encoder
    gemm_f32<1><<<dim3(DH / 128, B_ / 128), 256, 0, stream>>>(x, ew1, eb1, h, B_, DH, DIN);
    gemm_f32<0><<<dim3(DL / 128, B_ / 128), 256, 0, stream>>>(h, ew2, eb2, z, B_, DL, DH);

    // vector quantizer
    vq_score<<<dim3(NE / 128, B_ / 128), 256, 0, stream>>>(z, cbk, cn2, bval, bidx);
    vq_select<<<B_ / 4, 256, 0, stream>>>(bval, bidx, z, cbk, zq, part);
    loss_finalize<<<1, 256, 0, stream>>>(part, out + (size_t)B_ * DIN);

    // decoder
    gemm_f32<1><<<dim3(DH / 128, B_ / 128), 256, 0, stream>>>(zq, dw1, db1, h, B_, DH, DL);
    gemm_f32<2><<<dim3(DIN / 128, B_ / 128), 256, 0, stream>>>(h, dw2, db2, out, B_, DIN, DH);
}

// Round 4
// 491.101 us; speedup vs baseline: 8.9542x; 5.7634x over previous
//
#include <hip/hip_runtime.h>
#include <math.h>

typedef unsigned short u16;
typedef __bf16 bf16x8 __attribute__((ext_vector_type(8)));
typedef float  f32x4  __attribute__((ext_vector_type(4)));

constexpr int B_  = 16384;   // batch
constexpr int DIN = 1024;    // input dim
constexpr int DH  = 2048;    // hidden dim
constexpr int DL  = 256;     // latent dim
constexpr int NE  = 8192;    // codebook entries

__device__ __forceinline__ u16 f2bf(float f) {     // RTNE float->bf16
    union { float f; unsigned u; } v; v.f = f;
    unsigned r = v.u + 0x7fffu + ((v.u >> 16) & 1u);
    return (u16)(r >> 16);
}
__device__ __forceinline__ float bf2f(u16 h) {
    union { unsigned u; float f; } v; v.u = ((unsigned)h) << 16;
    return v.f;
}

#define GLD16(gp, lp)                                                  \
    __builtin_amdgcn_global_load_lds(                                  \
        (__attribute__((address_space(1))) void*)(gp),                 \
        (__attribute__((address_space(3))) void*)(lp), 16, 0, 0)

// ---------------------------------------------------------------------------
// cast fp32 -> bf16, 4 elts/thread (n % 1024 == 0)
// ---------------------------------------------------------------------------
__global__ __launch_bounds__(256)
void cast_bf16(const float* __restrict__ in, u16* __restrict__ out)
{
    const size_t i = ((size_t)blockIdx.x * 256 + threadIdx.x) * 4;
    float4 v = *(const float4*)(in + i);
    ushort4 o;
    o.x = f2bf(v.x); o.y = f2bf(v.y); o.z = f2bf(v.z); o.w = f2bf(v.w);
    *(ushort4*)(out + i) = o;
}

// ---------------------------------------------------------------------------
// transpose-cast: in [R][C] fp32 -> out [C][R] bf16.  32x32 LDS tile.
// ---------------------------------------------------------------------------
__global__ __launch_bounds__(256)
void transpose_cast(const float* __restrict__ in, u16* __restrict__ out,
                    int R, int C)
{
    __shared__ float t[32][33];
    const int tx = threadIdx.x & 31, ty = threadIdx.x >> 5;
    const long bx = blockIdx.x;   // C/32
    const long by = blockIdx.y;   // R/32
#pragma unroll
    for (int p = 0; p < 4; ++p)
        t[ty + p * 8][tx] = in[(by * 32 + ty + p * 8) * (long)C + bx * 32 + tx];
    __syncthreads();
#pragma unroll
    for (int p = 0; p < 4; ++p)
        out[(bx * 32 + ty + p * 8) * (long)R + by * 32 + tx] = f2bf(t[tx][ty + p * 8]);
}

// ---------------------------------------------------------------------------
// cn2[k] = 0.5 * ||codebook[k]||^2 (fp32). One wave per code.
// ---------------------------------------------------------------------------
__global__ __launch_bounds__(256)
void cn2_kernel(const float* __restrict__ cb, float* __restrict__ cn2)
{
    const int code = (blockIdx.x * 256 + threadIdx.x) >> 6;
    const int lane = threadIdx.x & 63;
    float4 v = *(const float4*)(cb + (long)code * DL + lane * 4);
    float s = fmaf(v.x, v.x, fmaf(v.y, v.y, fmaf(v.z, v.z, v.w * v.w)));
#pragma unroll
    for (int off = 32; off; off >>= 1) s += __shfl_down(s, off);
    if (lane == 0) cn2[code] = 0.5f * s;
}

// ---------------------------------------------------------------------------
// bf16 MFMA GEMM (m97 structure): C = epi(A @ B^T' + bias)
// A [M,K] bf16 row-major; Bt [N,K] bf16 row-major (i.e. B transposed).
// 128x128 tile, BK=32, 256 threads = 4 waves (2x2), each wave 64x64 out,
// 4x4 frags of v_mfma_f32_16x16x32_bf16. global_load_lds width 16.
// EPI: 0 = bias->bf16, 1 = bias+relu->bf16, 2 = bias+sigmoid->f32
// ---------------------------------------------------------------------------
template <int EPI>
__global__ __launch_bounds__(256)
void gemm_bt_bf16(const u16* __restrict__ A, const u16* __restrict__ Bt,
                  const float* __restrict__ bias, void* __restrict__ Cout,
                  int M, int N, int K)
{
    __shared__ __align__(16) u16 As[128 * 32];
    __shared__ __align__(16) u16 Bs[128 * 32];

    const int tid = threadIdx.x;
    const int w = tid >> 6, l = tid & 63;
    const int wr = w >> 1, wc = w & 1;
    const long bx = blockIdx.x, by = blockIdx.y;

    const int lr = l >> 2;            // staging: row-in-segment 0..15
    const int lc = (l & 3) * 8;       // staging: k-offset in shorts (16B)
    const int lg = l >> 4, lm = l & 15;  // frag: k-group / row-col index

    f32x4 acc[4][4] = {};

    for (int k0 = 0; k0 < K; k0 += 32) {
#pragma unroll
        for (int i = 0; i < 2; ++i) {
            const int seg = w * 2 + i;                 // 0..7 -> 16 rows each
            const u16* ga = A  + (size_t)(by * 128 + seg * 16 + lr) * K + k0 + lc;
            GLD16(ga, As + seg * 512);
            const u16* gb = Bt + (size_t)(bx * 128 + seg * 16 + lr) * K + k0 + lc;
            GLD16(gb, Bs + seg * 512);
        }
        __syncthreads();

        bf16x8 af[4], bfr[4];
#pragma unroll
        for (int m = 0; m < 4; ++m)
            af[m] = *(const bf16x8*)&As[(wr * 64 + m * 16 + lm) * 32 + lg * 8];
#pragma unroll
        for (int n = 0; n < 4; ++n)
            bfr[n] = *(const bf16x8*)&Bs[(wc * 64 + n * 16 + lm) * 32 + lg * 8];
#pragma unroll
        for (int m = 0; m < 4; ++m)
#pragma unroll
            for (int n = 0; n < 4; ++n)
                acc[m][n] = __builtin_amdgcn_mfma_f32_16x16x32_bf16(
                    af[m], bfr[n], acc[m][n], 0, 0, 0);
        __syncthreads();
    }

    // epilogue: C[row][col], row = by*128+wr*64+m*16+lg*4+j, col = bx*128+wc*64+n*16+lm
#pragma unroll
    for (int n = 0; n < 4; ++n) {
        const long col = bx * 128 + wc * 64 + n * 16 + lm;
        const float bb = bias[col];
#pragma unroll
        for (int m = 0; m < 4; ++m) {
#pragma unroll
            for (int j = 0; j < 4; ++j) {
                const long row = by * 128 + wr * 64 + m * 16 + lg * 4 + j;
                float e = acc[m][n][j] + bb;
                if (EPI == 1) e = fmaxf(e, 0.f);
                if (EPI == 2) {
                    e = 1.f / (1.f + expf(-e));
                    ((float*)Cout)[row * (long)N + col] = e;
                } else {
                    ((u16*)Cout)[row * (long)N + col] = f2bf(e);
                }
            }
        }
    }
}

// ---------------------------------------------------------------------------
// VQ phase 1 (MFMA): scores = 0.5*||c||^2 - z.c over a 128x128 tile,
// per-row argmin within tile (tie-break lowest code), write bval/bidx[row][bx].
// z [B_,256] bf16; cbt [NE,256] bf16 (codebook is already [N][K]).
// ---------------------------------------------------------------------------
__global__ __launch_bounds__(256)
void vq_score_mfma(const u16* __restrict__ z, const u16* __restrict__ cbt,
                   const float* __restrict__ cn2,
                   float* __restrict__ bval, int* __restrict__ bidx)
{
    __shared__ __align__(16) u16 As[128 * 32];
    __shared__ __align__(16) u16 Bs[128 * 32];
    __shared__ float s_bv[2][128];
    __shared__ int   s_bi[2][128];

    const int tid = threadIdx.x;
    const int w = tid >> 6, l = tid & 63;
    const int wr = w >> 1, wc = w & 1;
    const long bx = blockIdx.x;    // code tile (64)
    const long by = blockIdx.y;    // row tile (128)

    const int lr = l >> 2;
    const int lc = (l & 3) * 8;
    const int lg = l >> 4, lm = l & 15;

    f32x4 acc[4][4] = {};

    for (int k0 = 0; k0 < DL; k0 += 32) {
#pragma unroll
        for (int i = 0; i < 2; ++i) {
            const int seg = w * 2 + i;
            const u16* ga = z   + (size_t)(by * 128 + seg * 16 + lr) * DL + k0 + lc;
            GLD16(ga, As + seg * 512);
            const u16* gb = cbt + (size_t)(bx * 128 + seg * 16 + lr) * DL + k0 + lc;
            GLD16(gb, Bs + seg * 512);
        }
        __syncthreads();

        bf16x8 af[4], bfr[4];
#pragma unroll
        for (int m = 0; m < 4; ++m)
            af[m] = *(const bf16x8*)&As[(wr * 64 + m * 16 + lm) * 32 + lg * 8];
#pragma unroll
        for (int n = 0; n < 4; ++n)
            bfr[n] = *(const bf16x8*)&Bs[(wc * 64 + n * 16 + lm) * 32 + lg * 8];
#pragma unroll
        for (int m = 0; m < 4; ++m)
#pragma unroll
            for (int n = 0; n < 4; ++n)
                acc[m][n] = __builtin_amdgcn_mfma_f32_16x16x32_bf16(
                    af[m], bfr[n], acc[m][n], 0, 0, 0);
        __syncthreads();
    }

    // per-lane codes for its 4 n-frags
    float hc2[4]; int code[4];
#pragma unroll
    for (int n = 0; n < 4; ++n) {
        code[n] = (int)bx * 128 + wc * 64 + n * 16 + lm;
        hc2[n]  = cn2[code[n]];
    }

    // per (m,j) row: min over n (codes ascending -> strict < keeps lowest),
    // then shfl-reduce across the 16-lane group (tie-break lowest idx).
#pragma unroll
    for (int m = 0; m < 4; ++m) {
#pragma unroll
        for (int j = 0; j < 4; ++j) {
            float best = hc2[0] - acc[m][0][j];
            int   bi   = code[0];
#pragma unroll
            for (int n = 1; n < 4; ++n) {
                const float s = hc2[n] - acc[m][n][j];
                if (s < best) { best = s; bi = code[n]; }
            }
#pragma unroll
            for (int off = 1; off < 16; off <<= 1) {
                const float ov = __shfl_xor(best, off);
                const int   oi = __shfl_xor(bi, off);
                if (ov < best || (ov == best && oi < bi)) { best = ov; bi = oi; }
            }
            if (lm == 0) {
                const int rloc = wr * 64 + m * 16 + lg * 4 + j;
                s_bv[wc][rloc] = best;
                s_bi[wc][rloc] = bi;
            }
        }
    }
    __syncthreads();

    if (tid < 128) {
        const float v0 = s_bv[0][tid], v1 = s_bv[1][tid];
        const int   i0 = s_bi[0][tid], i1 = s_bi[1][tid];
        const bool take1 = (v1 < v0) || (v1 == v0 && i1 < i0);
        const long row = by * 128 + tid;
        bval[row * 64 + bx] = take1 ? v1 : v0;
        bidx[row * 64 + bx] = take1 ? i1 : i0;
    }
}

// ---------------------------------------------------------------------------
// VQ phase 2: reduce 64 candidates per row, gather z_q (bf16 out for decoder),
// loss partial per block. One wave per row; 4 rows per block.
// ---------------------------------------------------------------------------
__global__ __launch_bounds__(256)
void vq_select(const float* __restrict__ bval, const int* __restrict__ bidx,
               const u16* __restrict__ z, const float* __restrict__ cb,
               u16* __restrict__ zq, float* __restrict__ partial)
{
    __shared__ float s_red[4];
    const int tid  = threadIdx.x;
    const int w    = tid >> 6;
    const int lane = tid & 63;
    const long row = blockIdx.x * 4 + w;

    float v = bval[row * 64 + lane];
    int   i = bidx[row * 64 + lane];
#pragma unroll
    for (int off = 1; off < 64; off <<= 1) {
        const float ov = __shfl_xor(v, off);
        const int   oi = __shfl_xor(i, off);
        if (ov < v || (ov == v && oi < i)) { v = ov; i = oi; }
    }

    float4 c4 = *(const float4*)(cb + (long)i * DL + lane * 4);
    ushort4 zu = *(const ushort4*)(z + row * (long)DL + lane * 4);
    ushort4 qo;
    qo.x = f2bf(c4.x); qo.y = f2bf(c4.y); qo.z = f2bf(c4.z); qo.w = f2bf(c4.w);
    *(ushort4*)(zq + row * (long)DL + lane * 4) = qo;
    const float dx = c4.x - bf2f(zu.x), dy = c4.y - bf2f(zu.y);
    const float dz = c4.z - bf2f(zu.z), dw = c4.w - bf2f(zu.w);
    float ls = dx * dx + dy * dy + dz * dz + dw * dw;
#pragma unroll
    for (int off = 32; off; off >>= 1) ls += __shfl_down(ls, off);
    if (lane == 0) s_red[w] = ls;
    __syncthreads();
    if (tid == 0)
        partial[blockIdx.x] = s_red[0] + s_red[1] + s_red[2] + s_red[3];
}

// ---------------------------------------------------------------------------
// loss = 1.25 * sum(partial[4096]) / (B_*DL)
// ---------------------------------------------------------------------------
__global__ __launch_bounds__(256)
void loss_finalize(const float* __restrict__ partial, float* __restrict__ out)
{
    __shared__ float s_red[4];
    const int tid = threadIdx.x;
    float s = 0.f;
#pragma unroll
    for (int t = 0; t < 16; ++t) s += partial[tid + t * 256];
#pragma unroll
    for (int off = 32; off; off >>= 1) s += __shfl_down(s, off);
    if ((tid & 63) == 0) s_red[tid >> 6] = s;
    __syncthreads();
    if (tid == 0)
        out[0] = 1.25f * (s_red[0] + s_red[1] + s_red[2] + s_red[3])
                 / (float)((long)B_ * DL);
}

// ---------------------------------------------------------------------------
extern "C" void kernel_launch(void* const* d_in, const int* in_sizes, int n_in,
                              void* d_out, int out_size, void* d_ws, size_t ws_size,
                              hipStream_t stream)
{
    const float* x   = (const float*)d_in[0];
    const float* ew1 = (const float*)d_in[1];
    const float* eb1 = (const float*)d_in[2];
    const float* ew2 = (const float*)d_in[3];
    const float* eb2 = (const float*)d_in[4];
    const float* cbk = (const float*)d_in[5];
    const float* dw1 = (const float*)d_in[6];
    const float* db1 = (const float*)d_in[7];
    const float* dw2 = (const float*)d_in[8];
    const float* db2 = (const float*)d_in[9];
    float* out = (float*)d_out;

    char* p = (char*)d_ws;
    auto alloc = [&](size_t bytes) {
        char* r = p; p += (bytes + 255) & ~(size_t)255; return r;
    };
    u16*   x_bf  = (u16*)alloc((size_t)B_ * DIN * 2);
    u16*   h_bf  = (u16*)alloc((size_t)B_ * DH * 2);   // also decoder hidden
    u16*   z_bf  = (u16*)alloc((size_t)B_ * DL * 2);
    u16*   zq_bf = (u16*)alloc((size_t)B_ * DL * 2);
    u16*   cb_bf = (u16*)alloc((size_t)NE * DL * 2);
    u16*   w1t   = (u16*)alloc((size_t)DH * DIN * 2);  // [N][K] bf16
    u16*   w2t   = (u16*)alloc((size_t)DL * DH * 2);
    u16*   wd1t  = (u16*)alloc((size_t)DH * DL * 2);
    u16*   wd2t  = (u16*)alloc((size_t)DIN * DH * 2);
    float* cn2   = (float*)alloc((size_t)NE * 4);
    float* bval  = (float*)alloc((size_t)B_ * 64 * 4);
    int*   bidx  = (int*)alloc((size_t)B_ * 64 * 4);
    float* part  = (float*)alloc(4096 * 4);

    // casts / transposes (weights -> [N][K] bf16)
    cast_bf16<<<(size_t)B_ * DIN / 1024, 256, 0, stream>>>(x, x_bf);
    cast_bf16<<<(size_t)NE * DL / 1024, 256, 0, stream>>>(cbk, cb_bf);
    transpose_cast<<<dim3(DH / 32, DIN / 32), 256, 0, stream>>>(ew1, w1t, DIN, DH);
    transpose_cast<<<dim3(DL / 32, DH / 32), 256, 0, stream>>>(ew2, w2t, DH, DL);
    transpose_cast<<<dim3(DH / 32, DL / 32), 256, 0, stream>>>(dw1, wd1t, DL, DH);
    transpose_cast<<<dim3(DIN / 32, DH / 32), 256, 0, stream>>>(dw2, wd2t, DH, DIN);
    cn2_kernel<<<NE / 4, 256, 0, stream>>>(cbk, cn2);

    // encoder
    gemm_bt_bf16<1><<<dim3(DH / 128, B_ / 128), 256, 0, stream>>>(
        x_bf, w1t, eb1, h_bf, B_, DH, DIN);
    gemm_bt_bf16<0><<<dim3(DL / 128, B_ / 128), 256, 0, stream>>>(
        h_bf, w2t, eb2, z_bf, B_, DL, DH);

    // vector quantizer
    vq_score_mfma<<<dim3(NE / 128, B_ / 128), 256, 0, stream>>>(
        z_bf, cb_bf, cn2, bval, bidx);
    vq_select<<<B_ / 4, 256, 0, stream>>>(bval, bidx, z_bf, cbk, zq_bf, part);
    loss_finalize<<<1, 256, 0, stream>>>(part, out + (size_t)B_ * DIN);

    // decoder
    gemm_bt_bf16<1><<<dim3(DH / 128, B_ / 128), 256, 0, stream>>>(
        zq_bf, wd1t, db1, h_bf, B_, DH, DL);
    gemm_bt_bf16<2><<<dim3(DIN / 128, B_ / 128), 256, 0, stream>>>(
        h_bf, wd2t, db2, out, B_, DIN, DH);
}

// Round 5
// 409.825 us; speedup vs baseline: 10.7300x; 1.1983x over previous
//
#include <hip/hip_runtime.h>
#include <math.h>

typedef unsigned short u16;
typedef __bf16 bf16x8 __attribute__((ext_vector_type(8)));
typedef float  f32x4  __attribute__((ext_vector_type(4)));

constexpr int B_  = 16384;   // batch
constexpr int DIN = 1024;    // input dim
constexpr int DH  = 2048;    // hidden dim
constexpr int DL  = 256;     // latent dim
constexpr int NE  = 8192;    // codebook entries

__device__ __forceinline__ u16 f2bf(float f) {     // RTNE float->bf16
    union { float f; unsigned u; } v; v.f = f;
    unsigned r = v.u + 0x7fffu + ((v.u >> 16) & 1u);
    return (u16)(r >> 16);
}
__device__ __forceinline__ float bf2f(u16 h) {
    union { unsigned u; float f; } v; v.u = ((unsigned)h) << 16;
    return v.f;
}

#define GLD16(gp, lp)                                                  \
    __builtin_amdgcn_global_load_lds(                                  \
        (__attribute__((address_space(1))) void*)(gp),                 \
        (__attribute__((address_space(3))) void*)(lp), 16, 0, 0)

// ---------------------------------------------------------------------------
// cast fp32 -> bf16, 4 elts/thread (n % 1024 == 0)
// ---------------------------------------------------------------------------
__global__ __launch_bounds__(256)
void cast_bf16(const float* __restrict__ in, u16* __restrict__ out)
{
    const size_t i = ((size_t)blockIdx.x * 256 + threadIdx.x) * 4;
    float4 v = *(const float4*)(in + i);
    ushort4 o;
    o.x = f2bf(v.x); o.y = f2bf(v.y); o.z = f2bf(v.z); o.w = f2bf(v.w);
    *(ushort4*)(out + i) = o;
}

// ---------------------------------------------------------------------------
// transpose-cast: in [R][C] fp32 -> out [C][R] bf16.  32x32 LDS tile.
// ---------------------------------------------------------------------------
__global__ __launch_bounds__(256)
void transpose_cast(const float* __restrict__ in, u16* __restrict__ out,
                    int R, int C)
{
    __shared__ float t[32][33];
    const int tx = threadIdx.x & 31, ty = threadIdx.x >> 5;
    const long bx = blockIdx.x;   // C/32
    const long by = blockIdx.y;   // R/32
#pragma unroll
    for (int p = 0; p < 4; ++p)
        t[ty + p * 8][tx] = in[(by * 32 + ty + p * 8) * (long)C + bx * 32 + tx];
    __syncthreads();
#pragma unroll
    for (int p = 0; p < 4; ++p)
        out[(bx * 32 + ty + p * 8) * (long)R + by * 32 + tx] = f2bf(t[tx][ty + p * 8]);
}

// ---------------------------------------------------------------------------
// cn2[k] = 0.5 * ||codebook[k]||^2 (fp32). One wave per code.
// ---------------------------------------------------------------------------
__global__ __launch_bounds__(256)
void cn2_kernel(const float* __restrict__ cb, float* __restrict__ cn2)
{
    const int code = (blockIdx.x * 256 + threadIdx.x) >> 6;
    const int lane = threadIdx.x & 63;
    float4 v = *(const float4*)(cb + (long)code * DL + lane * 4);
    float s = fmaf(v.x, v.x, fmaf(v.y, v.y, fmaf(v.z, v.z, v.w * v.w)));
#pragma unroll
    for (int off = 32; off; off >>= 1) s += __shfl_down(s, off);
    if (lane == 0) cn2[code] = 0.5f * s;
}

// ---------------------------------------------------------------------------
// bf16 MFMA GEMM (m97 structure): C = epi(A @ B^T' + bias)
// A [M,K] bf16 row-major; Bt [N,K] bf16 row-major (i.e. B transposed).
// 128x128 tile, BK=32, 256 threads = 4 waves (2x2), each wave 64x64 out,
// 4x4 frags of v_mfma_f32_16x16x32_bf16. global_load_lds width 16.
// EPI: 0 = bias->bf16, 1 = bias+relu->bf16, 2 = bias+sigmoid->f32
// ---------------------------------------------------------------------------
template <int EPI>
__global__ __launch_bounds__(256)
void gemm_bt_bf16(const u16* __restrict__ A, const u16* __restrict__ Bt,
                  const float* __restrict__ bias, void* __restrict__ Cout,
                  int M, int N, int K)
{
    __shared__ __align__(16) u16 As[128 * 32];
    __shared__ __align__(16) u16 Bs[128 * 32];

    const int tid = threadIdx.x;
    const int w = tid >> 6, l = tid & 63;
    const int wr = w >> 1, wc = w & 1;
    const long bx = blockIdx.x, by = blockIdx.y;

    const int lr = l >> 2;            // staging: row-in-segment 0..15
    const int lc = (l & 3) * 8;       // staging: k-offset in shorts (16B)
    const int lg = l >> 4, lm = l & 15;  // frag: k-group / row-col index

    f32x4 acc[4][4] = {};

    for (int k0 = 0; k0 < K; k0 += 32) {
#pragma unroll
        for (int i = 0; i < 2; ++i) {
            const int seg = w * 2 + i;                 // 0..7 -> 16 rows each
            const u16* ga = A  + (size_t)(by * 128 + seg * 16 + lr) * K + k0 + lc;
            GLD16(ga, As + seg * 512);
            const u16* gb = Bt + (size_t)(bx * 128 + seg * 16 + lr) * K + k0 + lc;
            GLD16(gb, Bs + seg * 512);
        }
        __syncthreads();

        bf16x8 af[4], bfr[4];
#pragma unroll
        for (int m = 0; m < 4; ++m)
            af[m] = *(const bf16x8*)&As[(wr * 64 + m * 16 + lm) * 32 + lg * 8];
#pragma unroll
        for (int n = 0; n < 4; ++n)
            bfr[n] = *(const bf16x8*)&Bs[(wc * 64 + n * 16 + lm) * 32 + lg * 8];
#pragma unroll
        for (int m = 0; m < 4; ++m)
#pragma unroll
            for (int n = 0; n < 4; ++n)
                acc[m][n] = __builtin_amdgcn_mfma_f32_16x16x32_bf16(
                    af[m], bfr[n], acc[m][n], 0, 0, 0);
        __syncthreads();
    }

    // epilogue: row = by*128+wr*64+m*16+lg*4+j, col = bx*128+wc*64+n*16+lm
#pragma unroll
    for (int n = 0; n < 4; ++n) {
        const long col = bx * 128 + wc * 64 + n * 16 + lm;
        const float bb = bias[col];
#pragma unroll
        for (int m = 0; m < 4; ++m) {
#pragma unroll
            for (int j = 0; j < 4; ++j) {
                const long row = by * 128 + wr * 64 + m * 16 + lg * 4 + j;
                float e = acc[m][n][j] + bb;
                if (EPI == 1) e = fmaxf(e, 0.f);
                if (EPI == 2) {
                    e = 1.f / (1.f + expf(-e));
                    ((float*)Cout)[row * (long)N + col] = e;
                } else {
                    ((u16*)Cout)[row * (long)N + col] = f2bf(e);
                }
            }
        }
    }
}

// ---------------------------------------------------------------------------
// VQ phase 1 v2: register-resident A, LDS-streamed codebook.
// Block = 4 waves x 64 rows = 256 rows, scanning one code-eighth (1024).
// grid = 512 (64 row-tiles x 8 eighths; q = bx&7 pins eighth to an XCD L2).
// z rows staged to LDS once -> A-frags in registers (128 VGPR).
// Codebook streamed in 64-code tiles (32KB), double-buffered, ONE barrier
// per tile with 512 MFMA between barriers. LDS XOR-swizzle (involution on
// both the GLD source and the ds_read address) keeps b128 reads uniform
// across bank quads. Scores bitwise-identical to round-4 (same kg-ascending
// MFMA chain, same frag layouts); running per-lane argmin, tie-break lowest
// code; one lane-reduce at the end; writes val8/idx8[q][row].
// ---------------------------------------------------------------------------
__global__ __launch_bounds__(256, 2)
void vq_score2(const u16* __restrict__ z, const u16* __restrict__ cbt,
               const float* __restrict__ cn2,
               float* __restrict__ val8, int* __restrict__ idx8)
{
    __shared__ __align__(16) u16 lds[32768];   // 64KB: z-half / 2x32KB cb dbuf

    const int tid = threadIdx.x;
    const int w = tid >> 6, l = tid & 63;
    const int rq = blockIdx.x >> 3;       // row tile 0..63 (256 rows each)
    const int q  = blockIdx.x & 7;        // code eighth 0..7 (1024 codes)

    // staging source swizzle (constant per thread): slot s -> chunk s^(row&7)
    const int st_row8 = tid >> 5;                    // row mod 8 within stage
    const int st_s    = (tid & 31) ^ st_row8;        // swizzled 16B-chunk idx
    // frag-read swizzle components
    const int lg = l >> 4, lm = l & 15;
    const int swz_x = l & 7;                         // row&7 for frag rows

    // ---- stage z (two 128-row halves), load A-frags to registers ----
    bf16x8 af[4][8];
    const long zbase_row = (long)rq * 256;
#pragma unroll
    for (int h = 0; h < 2; ++h) {
        // stage 128 rows x 256 k (64KB) with swizzled source
#pragma unroll
        for (int i = 0; i < 16; ++i) {
            const int row = i * 8 + st_row8;         // 0..127
            const u16* g = z + (zbase_row + h * 128 + row) * DL + st_s * 8;
            GLD16(g, lds + ((size_t)i * 256 + w * 64) * 8);
        }
        __syncthreads();                             // drains vmcnt
        if ((w >> 1) == h) {
            const int lrow0 = (w & 1) * 64;
#pragma unroll
            for (int m = 0; m < 4; ++m) {
                const int lrow = lrow0 + m * 16 + lm;
#pragma unroll
                for (int kg = 0; kg < 8; ++kg) {
                    const int s = (kg * 4 + lg) ^ swz_x;
                    af[m][kg] = *(const bf16x8*)&lds[lrow * 256 + s * 8];
                }
            }
        }
        __syncthreads();
    }

    // ---- main loop: 16 tiles of 64 codes, double-buffered ----
    const int code00 = q * (NE / 8);                 // base of this eighth

    float bestv[16];
    int   besti[16];
#pragma unroll
    for (int k = 0; k < 16; ++k) { bestv[k] = 1e30f; besti[k] = 0; }

    auto stage_tile = [&](int t) {
        const int b = t & 1;
#pragma unroll
        for (int i = 0; i < 8; ++i) {
            const int c = i * 8 + st_row8;           // 0..63
            const u16* g = cbt + (size_t)(code00 + t * 64 + c) * DL + st_s * 8;
            GLD16(g, lds + ((size_t)b * 16384 + ((size_t)i * 256 + w * 64) * 8));
        }
    };

    stage_tile(0);
    __syncthreads();

    for (int t = 0; t < 16; ++t) {
        if (t < 15) stage_tile(t + 1);
        const u16* buf = lds + (size_t)(t & 1) * 16384;

#pragma unroll
        for (int n = 0; n < 4; ++n) {
            const int code_g = code00 + t * 64 + n * 16 + lm;
            const float cn2v = cn2[code_g];
            bf16x8 bfr[8];
#pragma unroll
            for (int kg = 0; kg < 8; ++kg) {
                const int lrow = n * 16 + lm;
                const int s = (kg * 4 + lg) ^ swz_x;
                bfr[kg] = *(const bf16x8*)&buf[lrow * 256 + s * 8];
            }
            f32x4 acc[4] = {};
#pragma unroll
            for (int kg = 0; kg < 8; ++kg)
#pragma unroll
                for (int m = 0; m < 4; ++m)
                    acc[m] = __builtin_amdgcn_mfma_f32_16x16x32_bf16(
                        af[m][kg], bfr[kg], acc[m], 0, 0, 0);
#pragma unroll
            for (int m = 0; m < 4; ++m)
#pragma unroll
                for (int j = 0; j < 4; ++j) {
                    const float s = cn2v - acc[m][j];
                    const int k16 = m * 4 + j;
                    if (s < bestv[k16]) { bestv[k16] = s; besti[k16] = code_g; }
                }
        }
        __syncthreads();
    }

    // ---- lane-reduce across the 16 code-lanes (tie-break lowest idx) ----
#pragma unroll
    for (int off = 1; off < 16; off <<= 1) {
#pragma unroll
        for (int k = 0; k < 16; ++k) {
            const float ov = __shfl_xor(bestv[k], off);
            const int   oi = __shfl_xor(besti[k], off);
            if (ov < bestv[k] || (ov == bestv[k] && oi < besti[k])) {
                bestv[k] = ov; besti[k] = oi;
            }
        }
    }
    if (lm == 0) {
#pragma unroll
        for (int m = 0; m < 4; ++m)
#pragma unroll
            for (int j = 0; j < 4; ++j) {
                const long row = zbase_row + w * 64 + m * 16 + lg * 4 + j;
                val8[(size_t)q * B_ + row] = bestv[m * 4 + j];
                idx8[(size_t)q * B_ + row] = besti[m * 4 + j];
            }
    }
}

// ---------------------------------------------------------------------------
// VQ phase 2: per row pick best of 8 eighth-candidates (tie-break lowest
// idx), gather z_q (bf16), loss partial per block. 256 rows per block.
// ---------------------------------------------------------------------------
__global__ __launch_bounds__(256)
void vq_select2(const float* __restrict__ val8, const int* __restrict__ idx8,
                const u16* __restrict__ z, const float* __restrict__ cb,
                u16* __restrict__ zq, float* __restrict__ partial)
{
    __shared__ int   s_idx[256];
    __shared__ float s_red[4];
    const int tid = threadIdx.x;
    const long row = (long)blockIdx.x * 256 + tid;

    float bv = val8[row];
    int   bi = idx8[row];
#pragma unroll
    for (int qq = 1; qq < 8; ++qq) {
        const float v = val8[(size_t)qq * B_ + row];
        const int   i = idx8[(size_t)qq * B_ + row];
        if (v < bv || (v == bv && i < bi)) { bv = v; bi = i; }
    }
    s_idx[tid] = bi;
    __syncthreads();

    float ls = 0.f;
    const int sub = tid & 7;
#pragma unroll
    for (int pass = 0; pass < 8; ++pass) {
        const int rl = pass * 32 + (tid >> 3);
        const int gi = s_idx[rl];
        const long rg = (long)blockIdx.x * 256 + rl;
#pragma unroll
        for (int tt = 0; tt < 8; ++tt) {
            const int d = sub * 4 + tt * 32;
            float4 c4 = *(const float4*)(cb + (long)gi * DL + d);
            ushort4 zu = *(const ushort4*)(z + rg * DL + d);
            ushort4 qo;
            qo.x = f2bf(c4.x); qo.y = f2bf(c4.y);
            qo.z = f2bf(c4.z); qo.w = f2bf(c4.w);
            *(ushort4*)(zq + rg * DL + d) = qo;
            const float dx = c4.x - bf2f(zu.x), dy = c4.y - bf2f(zu.y);
            const float dz = c4.z - bf2f(zu.z), dw = c4.w - bf2f(zu.w);
            ls += dx * dx + dy * dy + dz * dz + dw * dw;
        }
    }
#pragma unroll
    for (int off = 32; off; off >>= 1) ls += __shfl_down(ls, off);
    if ((tid & 63) == 0) s_red[tid >> 6] = ls;
    __syncthreads();
    if (tid == 0)
        partial[blockIdx.x] = s_red[0] + s_red[1] + s_red[2] + s_red[3];
}

// ---------------------------------------------------------------------------
// loss = 1.25 * sum(partial[64]) / (B_*DL)
// ---------------------------------------------------------------------------
__global__ __launch_bounds__(256)
void loss_finalize(const float* __restrict__ partial, float* __restrict__ out)
{
    __shared__ float s_red[4];
    const int tid = threadIdx.x;
    float s = (tid < 64) ? partial[tid] : 0.f;
#pragma unroll
    for (int off = 32; off; off >>= 1) s += __shfl_down(s, off);
    if ((tid & 63) == 0) s_red[tid >> 6] = s;
    __syncthreads();
    if (tid == 0)
        out[0] = 1.25f * (s_red[0] + s_red[1] + s_red[2] + s_red[3])
                 / (float)((long)B_ * DL);
}

// ---------------------------------------------------------------------------
extern "C" void kernel_launch(void* const* d_in, const int* in_sizes, int n_in,
                              void* d_out, int out_size, void* d_ws, size_t ws_size,
                              hipStream_t stream)
{
    const float* x   = (const float*)d_in[0];
    const float* ew1 = (const float*)d_in[1];
    const float* eb1 = (const float*)d_in[2];
    const float* ew2 = (const float*)d_in[3];
    const float* eb2 = (const float*)d_in[4];
    const float* cbk = (const float*)d_in[5];
    const float* dw1 = (const float*)d_in[6];
    const float* db1 = (const float*)d_in[7];
    const float* dw2 = (const float*)d_in[8];
    const float* db2 = (const float*)d_in[9];
    float* out = (float*)d_out;

    char* p = (char*)d_ws;
    auto alloc = [&](size_t bytes) {
        char* r = p; p += (bytes + 255) & ~(size_t)255; return r;
    };
    u16*   x_bf  = (u16*)alloc((size_t)B_ * DIN * 2);
    u16*   h_bf  = (u16*)alloc((size_t)B_ * DH * 2);   // also decoder hidden
    u16*   z_bf  = (u16*)alloc((size_t)B_ * DL * 2);
    u16*   zq_bf = (u16*)alloc((size_t)B_ * DL * 2);
    u16*   cb_bf = (u16*)alloc((size_t)NE * DL * 2);
    u16*   w1t   = (u16*)alloc((size_t)DH * DIN * 2);  // [N][K] bf16
    u16*   w2t   = (u16*)alloc((size_t)DL * DH * 2);
    u16*   wd1t  = (u16*)alloc((size_t)DH * DL * 2);
    u16*   wd2t  = (u16*)alloc((size_t)DIN * DH * 2);
    float* cn2   = (float*)alloc((size_t)NE * 4);
    float* val8  = (float*)alloc((size_t)8 * B_ * 4);
    int*   idx8  = (int*)alloc((size_t)8 * B_ * 4);
    float* part  = (float*)alloc(64 * 4);

    // casts / transposes (weights -> [N][K] bf16)
    cast_bf16<<<(size_t)B_ * DIN / 1024, 256, 0, stream>>>(x, x_bf);
    cast_bf16<<<(size_t)NE * DL / 1024, 256, 0, stream>>>(cbk, cb_bf);
    transpose_cast<<<dim3(DH / 32, DIN / 32), 256, 0, stream>>>(ew1, w1t, DIN, DH);
    transpose_cast<<<dim3(DL / 32, DH / 32), 256, 0, stream>>>(ew2, w2t, DH, DL);
    transpose_cast<<<dim3(DH / 32, DL / 32), 256, 0, stream>>>(dw1, wd1t, DL, DH);
    transpose_cast<<<dim3(DIN / 32, DH / 32), 256, 0, stream>>>(dw2, wd2t, DH, DIN);
    cn2_kernel<<<NE / 4, 256, 0, stream>>>(cbk, cn2);

    // encoder
    gemm_bt_bf16<1><<<dim3(DH / 128, B_ / 128), 256, 0, stream>>>(
        x_bf, w1t, eb1, h_bf, B_, DH, DIN);
    gemm_bt_bf16<0><<<dim3(DL / 128, B_ / 128), 256, 0, stream>>>(
        h_bf, w2t, eb2, z_bf, B_, DL, DH);

    // vector quantizer
    vq_score2<<<512, 256, 0, stream>>>(z_bf, cb_bf, cn2, val8, idx8);
    vq_select2<<<B_ / 256, 256, 0, stream>>>(val8, idx8, z_bf, cbk, zq_bf, part);
    loss_finalize<<<1, 256, 0, stream>>>(part, out + (size_t)B_ * DIN);

    // decoder
    gemm_bt_bf16<1><<<dim3(DH / 128, B_ / 128), 256, 0, stream>>>(
        zq_bf, wd1t, db1, h_bf, B_, DH, DL);
    gemm_bt_bf16<2><<<dim3(DIN / 128, B_ / 128), 256, 0, stream>>>(
        h_bf, wd2t, db2, out, B_, DIN, DH);
}

// Round 6
// 369.567 us; speedup vs baseline: 11.8988x; 1.1089x over previous
//
#include <hip/hip_runtime.h>
#include <math.h>

typedef unsigned short u16;
typedef __bf16 bf16x8 __attribute__((ext_vector_type(8)));
typedef float  f32x4  __attribute__((ext_vector_type(4)));

constexpr int B_  = 16384;   // batch
constexpr int DIN = 1024;    // input dim
constexpr int DH  = 2048;    // hidden dim
constexpr int DL  = 256;     // latent dim
constexpr int NE  = 8192;    // codebook entries

__device__ __forceinline__ u16 f2bf(float f) {     // RTNE float->bf16
    union { float f; unsigned u; } v; v.f = f;
    unsigned r = v.u + 0x7fffu + ((v.u >> 16) & 1u);
    return (u16)(r >> 16);
}
__device__ __forceinline__ float bf2f(u16 h) {
    union { unsigned u; float f; } v; v.u = ((unsigned)h) << 16;
    return v.f;
}

#define GLD16(gp, lp)                                                  \
    __builtin_amdgcn_global_load_lds(                                  \
        (__attribute__((address_space(1))) void*)(gp),                 \
        (__attribute__((address_space(3))) void*)(lp), 16, 0, 0)

// ---------------------------------------------------------------------------
// cast fp32 -> bf16, 4 elts/thread (n % 1024 == 0)
// ---------------------------------------------------------------------------
__global__ __launch_bounds__(256)
void cast_bf16(const float* __restrict__ in, u16* __restrict__ out)
{
    const size_t i = ((size_t)blockIdx.x * 256 + threadIdx.x) * 4;
    float4 v = *(const float4*)(in + i);
    ushort4 o;
    o.x = f2bf(v.x); o.y = f2bf(v.y); o.z = f2bf(v.z); o.w = f2bf(v.w);
    *(ushort4*)(out + i) = o;
}

// ---------------------------------------------------------------------------
// transpose-cast: in [R][C] fp32 -> out [C][R] bf16.  32x32 LDS tile.
// ---------------------------------------------------------------------------
__global__ __launch_bounds__(256)
void transpose_cast(const float* __restrict__ in, u16* __restrict__ out,
                    int R, int C)
{
    __shared__ float t[32][33];
    const int tx = threadIdx.x & 31, ty = threadIdx.x >> 5;
    const long bx = blockIdx.x;   // C/32
    const long by = blockIdx.y;   // R/32
#pragma unroll
    for (int p = 0; p < 4; ++p)
        t[ty + p * 8][tx] = in[(by * 32 + ty + p * 8) * (long)C + bx * 32 + tx];
    __syncthreads();
#pragma unroll
    for (int p = 0; p < 4; ++p)
        out[(bx * 32 + ty + p * 8) * (long)R + by * 32 + tx] = f2bf(t[tx][ty + p * 8]);
}

// ---------------------------------------------------------------------------
// cn2[k] = 0.5 * ||codebook[k]||^2 (fp32). One wave per code.
// ---------------------------------------------------------------------------
__global__ __launch_bounds__(256)
void cn2_kernel(const float* __restrict__ cb, float* __restrict__ cn2)
{
    const int code = (blockIdx.x * 256 + threadIdx.x) >> 6;
    const int lane = threadIdx.x & 63;
    float4 v = *(const float4*)(cb + (long)code * DL + lane * 4);
    float s = fmaf(v.x, v.x, fmaf(v.y, v.y, fmaf(v.z, v.z, v.w * v.w)));
#pragma unroll
    for (int off = 32; off; off >>= 1) s += __shfl_down(s, off);
    if (lane == 0) cn2[code] = 0.5f * s;
}

// ---------------------------------------------------------------------------
// bf16 MFMA GEMM, pipelined: C = epi(A @ Bt^T + bias)
// A [M,K] bf16 row-major; Bt [N,K] bf16 row-major.
// 128x128 tile, BK=32, 256 threads = 4 waves (2x2), each wave 64x64 out.
// T1: bijective XCD chunk-remap of the 1D grid (nwg % 8 == 0 for all our
//     shapes) -> each XCD owns a contiguous by-range; A-panels fetched once
//     per owning L2 instead of 8x.
// T3-minimum: LDS double-buffer, ONE barrier per K-step; next tile's
//     global_load_lds issued BEFORE current tile's ds_read+MFMA, so the
//     __syncthreads() vmcnt(0) drain lands after the compute.
// MFMA accumulation order identical to round-4 kernel -> bitwise-same C.
// EPI: 0 = bias->bf16, 1 = bias+relu->bf16, 2 = bias+sigmoid->f32
// ---------------------------------------------------------------------------
template <int EPI>
__global__ __launch_bounds__(256)
void gemm_bt_bf16(const u16* __restrict__ A, const u16* __restrict__ Bt,
                  const float* __restrict__ bias, void* __restrict__ Cout,
                  int M, int N, int K)
{
    __shared__ __align__(16) u16 As[2 * 4096];   // 2 x 128rows x 32k
    __shared__ __align__(16) u16 Bs[2 * 4096];

    const int tid = threadIdx.x;
    const int w = tid >> 6, l = tid & 63;
    const int wr = w >> 1, wc = w & 1;

    // bijective XCD chunk-remap (round-robin dispatch assumed: xcd = bid % 8)
    const int nbx   = N >> 7;
    const int nwg   = (M >> 7) * nbx;
    const int chunk = nwg >> 3;
    const int wg    = ((int)blockIdx.x & 7) * chunk + ((int)blockIdx.x >> 3);
    const long by   = wg / nbx;
    const long bx   = wg % nbx;

    const int lr = l >> 2;            // staging: row-in-segment 0..15
    const int lc = (l & 3) * 8;       // staging: k-offset in shorts (16B)
    const int lg = l >> 4, lm = l & 15;  // frag: k-group / row-col index

    const u16* Abase = A  + (size_t)(by * 128) * K;
    const u16* Bbase = Bt + (size_t)(bx * 128) * K;

    f32x4 acc[4][4] = {};

    auto stage = [&](int k0, int b) {
        u16* dA = As + b * 4096;
        u16* dB = Bs + b * 4096;
#pragma unroll
        for (int i = 0; i < 2; ++i) {
            const int seg = w * 2 + i;                 // 0..7 -> 16 rows each
            GLD16(Abase + (size_t)(seg * 16 + lr) * K + k0 + lc, dA + seg * 512);
            GLD16(Bbase + (size_t)(seg * 16 + lr) * K + k0 + lc, dB + seg * 512);
        }
    };

    const int NT = K >> 5;
    stage(0, 0);
    __syncthreads();

    for (int t = 0; t < NT; ++t) {
        if (t + 1 < NT) stage((t + 1) << 5, (t + 1) & 1);

        const u16* as = As + (t & 1) * 4096;
        const u16* bs = Bs + (t & 1) * 4096;
        bf16x8 af[4], bfr[4];
#pragma unroll
        for (int m = 0; m < 4; ++m)
            af[m] = *(const bf16x8*)&as[(wr * 64 + m * 16 + lm) * 32 + lg * 8];
#pragma unroll
        for (int n = 0; n < 4; ++n)
            bfr[n] = *(const bf16x8*)&bs[(wc * 64 + n * 16 + lm) * 32 + lg * 8];
#pragma unroll
        for (int m = 0; m < 4; ++m)
#pragma unroll
            for (int n = 0; n < 4; ++n)
                acc[m][n] = __builtin_amdgcn_mfma_f32_16x16x32_bf16(
                    af[m], bfr[n], acc[m][n], 0, 0, 0);
        __syncthreads();   // drains vmcnt (prefetch) + lgkmcnt, one barrier/step
    }

    // epilogue: row = by*128+wr*64+m*16+lg*4+j, col = bx*128+wc*64+n*16+lm
#pragma unroll
    for (int n = 0; n < 4; ++n) {
        const long col = bx * 128 + wc * 64 + n * 16 + lm;
        const float bb = bias[col];
#pragma unroll
        for (int m = 0; m < 4; ++m) {
#pragma unroll
            for (int j = 0; j < 4; ++j) {
                const long row = by * 128 + wr * 64 + m * 16 + lg * 4 + j;
                float e = acc[m][n][j] + bb;
                if (EPI == 1) e = fmaxf(e, 0.f);
                if (EPI == 2) {
                    e = 1.f / (1.f + expf(-e));
                    ((float*)Cout)[row * (long)N + col] = e;
                } else {
                    ((u16*)Cout)[row * (long)N + col] = f2bf(e);
                }
            }
        }
    }
}

// ---------------------------------------------------------------------------
// VQ phase 1 v2: register-resident A, LDS-streamed codebook.
// (unchanged from round 5 — no longer in the top-5)
// ---------------------------------------------------------------------------
__global__ __launch_bounds__(256, 2)
void vq_score2(const u16* __restrict__ z, const u16* __restrict__ cbt,
               const float* __restrict__ cn2,
               float* __restrict__ val8, int* __restrict__ idx8)
{
    __shared__ __align__(16) u16 lds[32768];   // 64KB: z-half / 2x32KB cb dbuf

    const int tid = threadIdx.x;
    const int w = tid >> 6, l = tid & 63;
    const int rq = blockIdx.x >> 3;       // row tile 0..63 (256 rows each)
    const int q  = blockIdx.x & 7;        // code eighth 0..7 (1024 codes)

    const int st_row8 = tid >> 5;
    const int st_s    = (tid & 31) ^ st_row8;
    const int lg = l >> 4, lm = l & 15;
    const int swz_x = l & 7;

    bf16x8 af[4][8];
    const long zbase_row = (long)rq * 256;
#pragma unroll
    for (int h = 0; h < 2; ++h) {
#pragma unroll
        for (int i = 0; i < 16; ++i) {
            const int row = i * 8 + st_row8;
            const u16* g = z + (zbase_row + h * 128 + row) * DL + st_s * 8;
            GLD16(g, lds + ((size_t)i * 256 + w * 64) * 8);
        }
        __syncthreads();
        if ((w >> 1) == h) {
            const int lrow0 = (w & 1) * 64;
#pragma unroll
            for (int m = 0; m < 4; ++m) {
                const int lrow = lrow0 + m * 16 + lm;
#pragma unroll
                for (int kg = 0; kg < 8; ++kg) {
                    const int s = (kg * 4 + lg) ^ swz_x;
                    af[m][kg] = *(const bf16x8*)&lds[lrow * 256 + s * 8];
                }
            }
        }
        __syncthreads();
    }

    const int code00 = q * (NE / 8);

    float bestv[16];
    int   besti[16];
#pragma unroll
    for (int k = 0; k < 16; ++k) { bestv[k] = 1e30f; besti[k] = 0; }

    auto stage_tile = [&](int t) {
        const int b = t & 1;
#pragma unroll
        for (int i = 0; i < 8; ++i) {
            const int c = i * 8 + st_row8;
            const u16* g = cbt + (size_t)(code00 + t * 64 + c) * DL + st_s * 8;
            GLD16(g, lds + ((size_t)b * 16384 + ((size_t)i * 256 + w * 64) * 8));
        }
    };

    stage_tile(0);
    __syncthreads();

    for (int t = 0; t < 16; ++t) {
        if (t < 15) stage_tile(t + 1);
        const u16* buf = lds + (size_t)(t & 1) * 16384;

#pragma unroll
        for (int n = 0; n < 4; ++n) {
            const int code_g = code00 + t * 64 + n * 16 + lm;
            const float cn2v = cn2[code_g];
            bf16x8 bfr[8];
#pragma unroll
            for (int kg = 0; kg < 8; ++kg) {
                const int lrow = n * 16 + lm;
                const int s = (kg * 4 + lg) ^ swz_x;
                bfr[kg] = *(const bf16x8*)&buf[lrow * 256 + s * 8];
            }
            f32x4 acc[4] = {};
#pragma unroll
            for (int kg = 0; kg < 8; ++kg)
#pragma unroll
                for (int m = 0; m < 4; ++m)
                    acc[m] = __builtin_amdgcn_mfma_f32_16x16x32_bf16(
                        af[m][kg], bfr[kg], acc[m], 0, 0, 0);
#pragma unroll
            for (int m = 0; m < 4; ++m)
#pragma unroll
                for (int j = 0; j < 4; ++j) {
                    const float s = cn2v - acc[m][j];
                    const int k16 = m * 4 + j;
                    if (s < bestv[k16]) { bestv[k16] = s; besti[k16] = code_g; }
                }
        }
        __syncthreads();
    }

#pragma unroll
    for (int off = 1; off < 16; off <<= 1) {
#pragma unroll
        for (int k = 0; k < 16; ++k) {
            const float ov = __shfl_xor(bestv[k], off);
            const int   oi = __shfl_xor(besti[k], off);
            if (ov < bestv[k] || (ov == bestv[k] && oi < besti[k])) {
                bestv[k] = ov; besti[k] = oi;
            }
        }
    }
    if (lm == 0) {
#pragma unroll
        for (int m = 0; m < 4; ++m)
#pragma unroll
            for (int j = 0; j < 4; ++j) {
                const long row = zbase_row + w * 64 + m * 16 + lg * 4 + j;
                val8[(size_t)q * B_ + row] = bestv[m * 4 + j];
                idx8[(size_t)q * B_ + row] = besti[m * 4 + j];
            }
    }
}

// ---------------------------------------------------------------------------
// VQ phase 2: per row pick best of 8 eighth-candidates, gather z_q (bf16),
// loss partial per block. 256 rows per block.
// ---------------------------------------------------------------------------
__global__ __launch_bounds__(256)
void vq_select2(const float* __restrict__ val8, const int* __restrict__ idx8,
                const u16* __restrict__ z, const float* __restrict__ cb,
                u16* __restrict__ zq, float* __restrict__ partial)
{
    __shared__ int   s_idx[256];
    __shared__ float s_red[4];
    const int tid = threadIdx.x;
    const long row = (long)blockIdx.x * 256 + tid;

    float bv = val8[row];
    int   bi = idx8[row];
#pragma unroll
    for (int qq = 1; qq < 8; ++qq) {
        const float v = val8[(size_t)qq * B_ + row];
        const int   i = idx8[(size_t)qq * B_ + row];
        if (v < bv || (v == bv && i < bi)) { bv = v; bi = i; }
    }
    s_idx[tid] = bi;
    __syncthreads();

    float ls = 0.f;
    const int sub = tid & 7;
#pragma unroll
    for (int pass = 0; pass < 8; ++pass) {
        const int rl = pass * 32 + (tid >> 3);
        const int gi = s_idx[rl];
        const long rg = (long)blockIdx.x * 256 + rl;
#pragma unroll
        for (int tt = 0; tt < 8; ++tt) {
            const int d = sub * 4 + tt * 32;
            float4 c4 = *(const float4*)(cb + (long)gi * DL + d);
            ushort4 zu = *(const ushort4*)(z + rg * DL + d);
            ushort4 qo;
            qo.x = f2bf(c4.x); qo.y = f2bf(c4.y);
            qo.z = f2bf(c4.z); qo.w = f2bf(c4.w);
            *(ushort4*)(zq + rg * DL + d) = qo;
            const float dx = c4.x - bf2f(zu.x), dy = c4.y - bf2f(zu.y);
            const float dz = c4.z - bf2f(zu.z), dw = c4.w - bf2f(zu.w);
            ls += dx * dx + dy * dy + dz * dz + dw * dw;
        }
    }
#pragma unroll
    for (int off = 32; off; off >>= 1) ls += __shfl_down(ls, off);
    if ((tid & 63) == 0) s_red[tid >> 6] = ls;
    __syncthreads();
    if (tid == 0)
        partial[blockIdx.x] = s_red[0] + s_red[1] + s_red[2] + s_red[3];
}

// ---------------------------------------------------------------------------
// loss = 1.25 * sum(partial[64]) / (B_*DL)
// ---------------------------------------------------------------------------
__global__ __launch_bounds__(256)
void loss_finalize(const float* __restrict__ partial, float* __restrict__ out)
{
    __shared__ float s_red[4];
    const int tid = threadIdx.x;
    float s = (tid < 64) ? partial[tid] : 0.f;
#pragma unroll
    for (int off = 32; off; off >>= 1) s += __shfl_down(s, off);
    if ((tid & 63) == 0) s_red[tid >> 6] = s;
    __syncthreads();
    if (tid == 0)
        out[0] = 1.25f * (s_red[0] + s_red[1] + s_red[2] + s_red[3])
                 / (float)((long)B_ * DL);
}

// ---------------------------------------------------------------------------
extern "C" void kernel_launch(void* const* d_in, const int* in_sizes, int n_in,
                              void* d_out, int out_size, void* d_ws, size_t ws_size,
                              hipStream_t stream)
{
    const float* x   = (const float*)d_in[0];
    const float* ew1 = (const float*)d_in[1];
    const float* eb1 = (const float*)d_in[2];
    const float* ew2 = (const float*)d_in[3];
    const float* eb2 = (const float*)d_in[4];
    const float* cbk = (const float*)d_in[5];
    const float* dw1 = (const float*)d_in[6];
    const float* db1 = (const float*)d_in[7];
    const float* dw2 = (const float*)d_in[8];
    const float* db2 = (const float*)d_in[9];
    float* out = (float*)d_out;

    char* p = (char*)d_ws;
    auto alloc = [&](size_t bytes) {
        char* r = p; p += (bytes + 255) & ~(size_t)255; return r;
    };
    u16*   x_bf  = (u16*)alloc((size_t)B_ * DIN * 2);
    u16*   h_bf  = (u16*)alloc((size_t)B_ * DH * 2);   // also decoder hidden
    u16*   z_bf  = (u16*)alloc((size_t)B_ * DL * 2);
    u16*   zq_bf = (u16*)alloc((size_t)B_ * DL * 2);
    u16*   cb_bf = (u16*)alloc((size_t)NE * DL * 2);
    u16*   w1t   = (u16*)alloc((size_t)DH * DIN * 2);  // [N][K] bf16
    u16*   w2t   = (u16*)alloc((size_t)DL * DH * 2);
    u16*   wd1t  = (u16*)alloc((size_t)DH * DL * 2);
    u16*   wd2t  = (u16*)alloc((size_t)DIN * DH * 2);
    float* cn2   = (float*)alloc((size_t)NE * 4);
    float* val8  = (float*)alloc((size_t)8 * B_ * 4);
    int*   idx8  = (int*)alloc((size_t)8 * B_ * 4);
    float* part  = (float*)alloc(64 * 4);

    // casts / transposes (weights -> [N][K] bf16)
    cast_bf16<<<(size_t)B_ * DIN / 1024, 256, 0, stream>>>(x, x_bf);
    cast_bf16<<<(size_t)NE * DL / 1024, 256, 0, stream>>>(cbk, cb_bf);
    transpose_cast<<<dim3(DH / 32, DIN / 32), 256, 0, stream>>>(ew1, w1t, DIN, DH);
    transpose_cast<<<dim3(DL / 32, DH / 32), 256, 0, stream>>>(ew2, w2t, DH, DL);
    transpose_cast<<<dim3(DH / 32, DL / 32), 256, 0, stream>>>(dw1, wd1t, DL, DH);
    transpose_cast<<<dim3(DIN / 32, DH / 32), 256, 0, stream>>>(dw2, wd2t, DH, DIN);
    cn2_kernel<<<NE / 4, 256, 0, stream>>>(cbk, cn2);

    // encoder (1D grids, XCD-remapped inside)
    gemm_bt_bf16<1><<<(B_ / 128) * (DH / 128), 256, 0, stream>>>(
        x_bf, w1t, eb1, h_bf, B_, DH, DIN);
    gemm_bt_bf16<0><<<(B_ / 128) * (DL / 128), 256, 0, stream>>>(
        h_bf, w2t, eb2, z_bf, B_, DL, DH);

    // vector quantizer
    vq_score2<<<512, 256, 0, stream>>>(z_bf, cb_bf, cn2, val8, idx8);
    vq_select2<<<B_ / 256, 256, 0, stream>>>(val8, idx8, z_bf, cbk, zq_bf, part);
    loss_finalize<<<1, 256, 0, stream>>>(part, out + (size_t)B_ * DIN);

    // decoder
    gemm_bt_bf16<1><<<(B_ / 128) * (DH / 128), 256, 0, stream>>>(
        zq_bf, wd1t, db1, h_bf, B_, DH, DL);
    gemm_bt_bf16<2><<<(B_ / 128) * (DIN / 128), 256, 0, stream>>>(
        h_bf, wd2t, db2, out, B_, DIN, DH);
}

// Round 7
// 340.382 us; speedup vs baseline: 12.9190x; 1.0857x over previous
//
#include <hip/hip_runtime.h>
#include <math.h>

typedef unsigned short u16;
typedef __bf16 bf16x8 __attribute__((ext_vector_type(8)));
typedef float  f32x4  __attribute__((ext_vector_type(4)));

constexpr int B_  = 16384;   // batch
constexpr int DIN = 1024;    // input dim
constexpr int DH  = 2048;    // hidden dim
constexpr int DL  = 256;     // latent dim
constexpr int NE  = 8192;    // codebook entries

__device__ __forceinline__ u16 f2bf(float f) {     // RTNE float->bf16
    union { float f; unsigned u; } v; v.f = f;
    unsigned r = v.u + 0x7fffu + ((v.u >> 16) & 1u);
    return (u16)(r >> 16);
}
__device__ __forceinline__ float bf2f(u16 h) {
    union { unsigned u; float f; } v; v.u = ((unsigned)h) << 16;
    return v.f;
}

#define GLD16(gp, lp)                                                  \
    __builtin_amdgcn_global_load_lds(                                  \
        (__attribute__((address_space(1))) void*)(gp),                 \
        (__attribute__((address_space(3))) void*)(lp), 16, 0, 0)

// ---------------------------------------------------------------------------
// cast fp32 -> bf16, 4 elts/thread (n % 1024 == 0)
// ---------------------------------------------------------------------------
__global__ __launch_bounds__(256)
void cast_bf16(const float* __restrict__ in, u16* __restrict__ out)
{
    const size_t i = ((size_t)blockIdx.x * 256 + threadIdx.x) * 4;
    float4 v = *(const float4*)(in + i);
    ushort4 o;
    o.x = f2bf(v.x); o.y = f2bf(v.y); o.z = f2bf(v.z); o.w = f2bf(v.w);
    *(ushort4*)(out + i) = o;
}

// ---------------------------------------------------------------------------
// transpose-cast: in [R][C] fp32 -> out [C][R] bf16.  32x32 LDS tile.
// ---------------------------------------------------------------------------
__global__ __launch_bounds__(256)
void transpose_cast(const float* __restrict__ in, u16* __restrict__ out,
                    int R, int C)
{
    __shared__ float t[32][33];
    const int tx = threadIdx.x & 31, ty = threadIdx.x >> 5;
    const long bx = blockIdx.x;   // C/32
    const long by = blockIdx.y;   // R/32
#pragma unroll
    for (int p = 0; p < 4; ++p)
        t[ty + p * 8][tx] = in[(by * 32 + ty + p * 8) * (long)C + bx * 32 + tx];
    __syncthreads();
#pragma unroll
    for (int p = 0; p < 4; ++p)
        out[(bx * 32 + ty + p * 8) * (long)R + by * 32 + tx] = f2bf(t[tx][ty + p * 8]);
}

// ---------------------------------------------------------------------------
// cn2[k] = 0.5 * ||codebook[k]||^2 (fp32). One wave per code.
// ---------------------------------------------------------------------------
__global__ __launch_bounds__(256)
void cn2_kernel(const float* __restrict__ cb, float* __restrict__ cn2)
{
    const int code = (blockIdx.x * 256 + threadIdx.x) >> 6;
    const int lane = threadIdx.x & 63;
    float4 v = *(const float4*)(cb + (long)code * DL + lane * 4);
    float s = fmaf(v.x, v.x, fmaf(v.y, v.y, fmaf(v.z, v.z, v.w * v.w)));
#pragma unroll
    for (int off = 32; off; off >>= 1) s += __shfl_down(s, off);
    if (lane == 0) cn2[code] = 0.5f * s;
}

// ---------------------------------------------------------------------------
// BIG bf16 MFMA GEMM: BM=256, BN=128, BK=32. 512 threads = 8 waves (4M x 2N),
// wave output 64x64 (4x4 frags of 16x16x32). 87 FLOP/staged-byte (vs 64 at
// 128^2) -> under the per-CU L2 BW ceiling. XOR-swizzled LDS (both-sides
// involution: source chunk ^= row&3 at stage, read chunk = lg ^ (lm&3)) ->
// fragment b128 reads spread over all 32 banks (2-way, free).
// T1 bijective XCD remap on the 1D grid. One __syncthreads per K-step
// (stage-next -> ds_read+MFMA -> barrier), same proven structure as r6.
// K-accumulation order identical -> bitwise-same C.
// EPI: 1 = bias+relu->bf16, 2 = bias+sigmoid->f32
// ---------------------------------------------------------------------------
template <int EPI>
__global__ __launch_bounds__(512, 4)
void gemm_big_bf16(const u16* __restrict__ A, const u16* __restrict__ Bt,
                   const float* __restrict__ bias, void* __restrict__ Cout,
                   int M, int N, int K)
{
    __shared__ __align__(16) u16 As[2][256 * 32];   // 2 x 16 KB
    __shared__ __align__(16) u16 Bs[2][128 * 32];   // 2 x  8 KB

    const int tid = threadIdx.x;
    const int w = tid >> 6, l = tid & 63;
    const int wm = w >> 1, wn = w & 1;

    // bijective XCD chunk-remap (nwg % 8 == 0 for all our shapes)
    const int nbx   = N >> 7;
    const int nwg   = (M >> 8) * nbx;
    const int chunk = nwg >> 3;
    const int wg    = ((int)blockIdx.x & 7) * chunk + ((int)blockIdx.x >> 3);
    const long by   = wg / nbx;
    const long bx   = wg % nbx;

    const int lr  = l >> 2;                  // row within 16-row segment
    const int lsw = (l & 3) ^ (lr & 3);      // swizzled source chunk (16B)
    const int lg  = l >> 4, lm = l & 15;     // frag k-group / row index
    const int rch = (0 ^ (lm & 3));          // read-chunk base (xor key lm&3)

    const u16* Abase = A  + (size_t)(by * 256) * K;
    const u16* Bbase = Bt + (size_t)(bx * 128) * K;

    f32x4 acc[4][4] = {};

    auto stage = [&](int k0, int b) {
        u16* dA = &As[b][0];
        u16* dB = &Bs[b][0];
#pragma unroll
        for (int i = 0; i < 2; ++i) {
            const int seg = w * 2 + i;       // 0..15 -> A rows seg*16..
            GLD16(Abase + (size_t)(seg * 16 + lr) * K + k0 + lsw * 8,
                  dA + seg * 512);
        }
        // B: 128 rows, segment = w
        GLD16(Bbase + (size_t)(w * 16 + lr) * K + k0 + lsw * 8,
              dB + w * 512);
    };

    const int NT = K >> 5;
    stage(0, 0);
    __syncthreads();

    const int sx = lm & 3;                   // read-side xor key
    for (int t = 0; t < NT; ++t) {
        if (t + 1 < NT) stage((t + 1) << 5, (t + 1) & 1);

        const u16* as = &As[t & 1][0];
        const u16* bs = &Bs[t & 1][0];
        bf16x8 af[4], bfr[4];
#pragma unroll
        for (int m = 0; m < 4; ++m) {
            const int R = wm * 64 + m * 16 + lm;
            af[m] = *(const bf16x8*)&as[R * 32 + ((lg ^ sx) * 8)];
        }
#pragma unroll
        for (int n = 0; n < 4; ++n) {
            const int R = wn * 64 + n * 16 + lm;
            bfr[n] = *(const bf16x8*)&bs[R * 32 + ((lg ^ sx) * 8)];
        }
#pragma unroll
        for (int m = 0; m < 4; ++m)
#pragma unroll
            for (int n = 0; n < 4; ++n)
                acc[m][n] = __builtin_amdgcn_mfma_f32_16x16x32_bf16(
                    af[m], bfr[n], acc[m][n], 0, 0, 0);
        __syncthreads();
    }

    // epilogue: row = by*256+wm*64+m*16+lg*4+j, col = bx*128+wn*64+n*16+lm
#pragma unroll
    for (int n = 0; n < 4; ++n) {
        const long col = bx * 128 + wn * 64 + n * 16 + lm;
        const float bb = bias[col];
#pragma unroll
        for (int m = 0; m < 4; ++m) {
#pragma unroll
            for (int j = 0; j < 4; ++j) {
                const long row = by * 256 + wm * 64 + m * 16 + lg * 4 + j;
                float e = acc[m][n][j] + bb;
                if (EPI == 1) e = fmaxf(e, 0.f);
                if (EPI == 2) {
                    e = 1.f / (1.f + expf(-e));
                    ((float*)Cout)[row * (long)N + col] = e;
                } else {
                    ((u16*)Cout)[row * (long)N + col] = f2bf(e);
                }
            }
        }
    }
}

// ---------------------------------------------------------------------------
// 128^2 bf16 MFMA GEMM (round-6 version) — kept for GEMM2 (N=256).
// EPI: 0 = bias->bf16
// ---------------------------------------------------------------------------
template <int EPI>
__global__ __launch_bounds__(256)
void gemm_bt_bf16(const u16* __restrict__ A, const u16* __restrict__ Bt,
                  const float* __restrict__ bias, void* __restrict__ Cout,
                  int M, int N, int K)
{
    __shared__ __align__(16) u16 As[2 * 4096];
    __shared__ __align__(16) u16 Bs[2 * 4096];

    const int tid = threadIdx.x;
    const int w = tid >> 6, l = tid & 63;
    const int wr = w >> 1, wc = w & 1;

    const int nbx   = N >> 7;
    const int nwg   = (M >> 7) * nbx;
    const int chunk = nwg >> 3;
    const int wg    = ((int)blockIdx.x & 7) * chunk + ((int)blockIdx.x >> 3);
    const long by   = wg / nbx;
    const long bx   = wg % nbx;

    const int lr = l >> 2;
    const int lc = (l & 3) * 8;
    const int lg = l >> 4, lm = l & 15;

    const u16* Abase = A  + (size_t)(by * 128) * K;
    const u16* Bbase = Bt + (size_t)(bx * 128) * K;

    f32x4 acc[4][4] = {};

    auto stage = [&](int k0, int b) {
        u16* dA = As + b * 4096;
        u16* dB = Bs + b * 4096;
#pragma unroll
        for (int i = 0; i < 2; ++i) {
            const int seg = w * 2 + i;
            GLD16(Abase + (size_t)(seg * 16 + lr) * K + k0 + lc, dA + seg * 512);
            GLD16(Bbase + (size_t)(seg * 16 + lr) * K + k0 + lc, dB + seg * 512);
        }
    };

    const int NT = K >> 5;
    stage(0, 0);
    __syncthreads();

    for (int t = 0; t < NT; ++t) {
        if (t + 1 < NT) stage((t + 1) << 5, (t + 1) & 1);

        const u16* as = As + (t & 1) * 4096;
        const u16* bs = Bs + (t & 1) * 4096;
        bf16x8 af[4], bfr[4];
#pragma unroll
        for (int m = 0; m < 4; ++m)
            af[m] = *(const bf16x8*)&as[(wr * 64 + m * 16 + lm) * 32 + lg * 8];
#pragma unroll
        for (int n = 0; n < 4; ++n)
            bfr[n] = *(const bf16x8*)&bs[(wc * 64 + n * 16 + lm) * 32 + lg * 8];
#pragma unroll
        for (int m = 0; m < 4; ++m)
#pragma unroll
            for (int n = 0; n < 4; ++n)
                acc[m][n] = __builtin_amdgcn_mfma_f32_16x16x32_bf16(
                    af[m], bfr[n], acc[m][n], 0, 0, 0);
        __syncthreads();
    }

#pragma unroll
    for (int n = 0; n < 4; ++n) {
        const long col = bx * 128 + wc * 64 + n * 16 + lm;
        const float bb = bias[col];
#pragma unroll
        for (int m = 0; m < 4; ++m) {
#pragma unroll
            for (int j = 0; j < 4; ++j) {
                const long row = by * 128 + wr * 64 + m * 16 + lg * 4 + j;
                float e = acc[m][n][j] + bb;
                if (EPI == 1) e = fmaxf(e, 0.f);
                if (EPI == 2) {
                    e = 1.f / (1.f + expf(-e));
                    ((float*)Cout)[row * (long)N + col] = e;
                } else {
                    ((u16*)Cout)[row * (long)N + col] = f2bf(e);
                }
            }
        }
    }
}

// ---------------------------------------------------------------------------
// VQ phase 1 v2: register-resident A, LDS-streamed codebook (unchanged).
// ---------------------------------------------------------------------------
__global__ __launch_bounds__(256, 2)
void vq_score2(const u16* __restrict__ z, const u16* __restrict__ cbt,
               const float* __restrict__ cn2,
               float* __restrict__ val8, int* __restrict__ idx8)
{
    __shared__ __align__(16) u16 lds[32768];

    const int tid = threadIdx.x;
    const int w = tid >> 6, l = tid & 63;
    const int rq = blockIdx.x >> 3;
    const int q  = blockIdx.x & 7;

    const int st_row8 = tid >> 5;
    const int st_s    = (tid & 31) ^ st_row8;
    const int lg = l >> 4, lm = l & 15;
    const int swz_x = l & 7;

    bf16x8 af[4][8];
    const long zbase_row = (long)rq * 256;
#pragma unroll
    for (int h = 0; h < 2; ++h) {
#pragma unroll
        for (int i = 0; i < 16; ++i) {
            const int row = i * 8 + st_row8;
            const u16* g = z + (zbase_row + h * 128 + row) * DL + st_s * 8;
            GLD16(g, lds + ((size_t)i * 256 + w * 64) * 8);
        }
        __syncthreads();
        if ((w >> 1) == h) {
            const int lrow0 = (w & 1) * 64;
#pragma unroll
            for (int m = 0; m < 4; ++m) {
                const int lrow = lrow0 + m * 16 + lm;
#pragma unroll
                for (int kg = 0; kg < 8; ++kg) {
                    const int s = (kg * 4 + lg) ^ swz_x;
                    af[m][kg] = *(const bf16x8*)&lds[lrow * 256 + s * 8];
                }
            }
        }
        __syncthreads();
    }

    const int code00 = q * (NE / 8);

    float bestv[16];
    int   besti[16];
#pragma unroll
    for (int k = 0; k < 16; ++k) { bestv[k] = 1e30f; besti[k] = 0; }

    auto stage_tile = [&](int t) {
        const int b = t & 1;
#pragma unroll
        for (int i = 0; i < 8; ++i) {
            const int c = i * 8 + st_row8;
            const u16* g = cbt + (size_t)(code00 + t * 64 + c) * DL + st_s * 8;
            GLD16(g, lds + ((size_t)b * 16384 + ((size_t)i * 256 + w * 64) * 8));
        }
    };

    stage_tile(0);
    __syncthreads();

    for (int t = 0; t < 16; ++t) {
        if (t < 15) stage_tile(t + 1);
        const u16* buf = lds + (size_t)(t & 1) * 16384;

#pragma unroll
        for (int n = 0; n < 4; ++n) {
            const int code_g = code00 + t * 64 + n * 16 + lm;
            const float cn2v = cn2[code_g];
            bf16x8 bfr[8];
#pragma unroll
            for (int kg = 0; kg < 8; ++kg) {
                const int lrow = n * 16 + lm;
                const int s = (kg * 4 + lg) ^ swz_x;
                bfr[kg] = *(const bf16x8*)&buf[lrow * 256 + s * 8];
            }
            f32x4 acc[4] = {};
#pragma unroll
            for (int kg = 0; kg < 8; ++kg)
#pragma unroll
                for (int m = 0; m < 4; ++m)
                    acc[m] = __builtin_amdgcn_mfma_f32_16x16x32_bf16(
                        af[m][kg], bfr[kg], acc[m], 0, 0, 0);
#pragma unroll
            for (int m = 0; m < 4; ++m)
#pragma unroll
                for (int j = 0; j < 4; ++j) {
                    const float s = cn2v - acc[m][j];
                    const int k16 = m * 4 + j;
                    if (s < bestv[k16]) { bestv[k16] = s; besti[k16] = code_g; }
                }
        }
        __syncthreads();
    }

#pragma unroll
    for (int off = 1; off < 16; off <<= 1) {
#pragma unroll
        for (int k = 0; k < 16; ++k) {
            const float ov = __shfl_xor(bestv[k], off);
            const int   oi = __shfl_xor(besti[k], off);
            if (ov < bestv[k] || (ov == bestv[k] && oi < besti[k])) {
                bestv[k] = ov; besti[k] = oi;
            }
        }
    }
    if (lm == 0) {
#pragma unroll
        for (int m = 0; m < 4; ++m)
#pragma unroll
            for (int j = 0; j < 4; ++j) {
                const long row = zbase_row + w * 64 + m * 16 + lg * 4 + j;
                val8[(size_t)q * B_ + row] = bestv[m * 4 + j];
                idx8[(size_t)q * B_ + row] = besti[m * 4 + j];
            }
    }
}

// ---------------------------------------------------------------------------
// VQ phase 2: per row pick best of 8 candidates, gather z_q, loss partials.
// ---------------------------------------------------------------------------
__global__ __launch_bounds__(256)
void vq_select2(const float* __restrict__ val8, const int* __restrict__ idx8,
                const u16* __restrict__ z, const float* __restrict__ cb,
                u16* __restrict__ zq, float* __restrict__ partial)
{
    __shared__ int   s_idx[256];
    __shared__ float s_red[4];
    const int tid = threadIdx.x;
    const long row = (long)blockIdx.x * 256 + tid;

    float bv = val8[row];
    int   bi = idx8[row];
#pragma unroll
    for (int qq = 1; qq < 8; ++qq) {
        const float v = val8[(size_t)qq * B_ + row];
        const int   i = idx8[(size_t)qq * B_ + row];
        if (v < bv || (v == bv && i < bi)) { bv = v; bi = i; }
    }
    s_idx[tid] = bi;
    __syncthreads();

    float ls = 0.f;
    const int sub = tid & 7;
#pragma unroll
    for (int pass = 0; pass < 8; ++pass) {
        const int rl = pass * 32 + (tid >> 3);
        const int gi = s_idx[rl];
        const long rg = (long)blockIdx.x * 256 + rl;
#pragma unroll
        for (int tt = 0; tt < 8; ++tt) {
            const int d = sub * 4 + tt * 32;
            float4 c4 = *(const float4*)(cb + (long)gi * DL + d);
            ushort4 zu = *(const ushort4*)(z + rg * DL + d);
            ushort4 qo;
            qo.x = f2bf(c4.x); qo.y = f2bf(c4.y);
            qo.z = f2bf(c4.z); qo.w = f2bf(c4.w);
            *(ushort4*)(zq + rg * DL + d) = qo;
            const float dx = c4.x - bf2f(zu.x), dy = c4.y - bf2f(zu.y);
            const float dz = c4.z - bf2f(zu.z), dw = c4.w - bf2f(zu.w);
            ls += dx * dx + dy * dy + dz * dz + dw * dw;
        }
    }
#pragma unroll
    for (int off = 32; off; off >>= 1) ls += __shfl_down(ls, off);
    if ((tid & 63) == 0) s_red[tid >> 6] = ls;
    __syncthreads();
    if (tid == 0)
        partial[blockIdx.x] = s_red[0] + s_red[1] + s_red[2] + s_red[3];
}

// ---------------------------------------------------------------------------
// loss = 1.25 * sum(partial[64]) / (B_*DL)
// ---------------------------------------------------------------------------
__global__ __launch_bounds__(256)
void loss_finalize(const float* __restrict__ partial, float* __restrict__ out)
{
    __shared__ float s_red[4];
    const int tid = threadIdx.x;
    float s = (tid < 64) ? partial[tid] : 0.f;
#pragma unroll
    for (int off = 32; off; off >>= 1) s += __shfl_down(s, off);
    if ((tid & 63) == 0) s_red[tid >> 6] = s;
    __syncthreads();
    if (tid == 0)
        out[0] = 1.25f * (s_red[0] + s_red[1] + s_red[2] + s_red[3])
                 / (float)((long)B_ * DL);
}

// ---------------------------------------------------------------------------
extern "C" void kernel_launch(void* const* d_in, const int* in_sizes, int n_in,
                              void* d_out, int out_size, void* d_ws, size_t ws_size,
                              hipStream_t stream)
{
    const float* x   = (const float*)d_in[0];
    const float* ew1 = (const float*)d_in[1];
    const float* eb1 = (const float*)d_in[2];
    const float* ew2 = (const float*)d_in[3];
    const float* eb2 = (const float*)d_in[4];
    const float* cbk = (const float*)d_in[5];
    const float* dw1 = (const float*)d_in[6];
    const float* db1 = (const float*)d_in[7];
    const float* dw2 = (const float*)d_in[8];
    const float* db2 = (const float*)d_in[9];
    float* out = (float*)d_out;

    char* p = (char*)d_ws;
    auto alloc = [&](size_t bytes) {
        char* r = p; p += (bytes + 255) & ~(size_t)255; return r;
    };
    u16*   x_bf  = (u16*)alloc((size_t)B_ * DIN * 2);
    u16*   h_bf  = (u16*)alloc((size_t)B_ * DH * 2);   // also decoder hidden
    u16*   z_bf  = (u16*)alloc((size_t)B_ * DL * 2);
    u16*   zq_bf = (u16*)alloc((size_t)B_ * DL * 2);
    u16*   cb_bf = (u16*)alloc((size_t)NE * DL * 2);
    u16*   w1t   = (u16*)alloc((size_t)DH * DIN * 2);  // [N][K] bf16
    u16*   w2t   = (u16*)alloc((size_t)DL * DH * 2);
    u16*   wd1t  = (u16*)alloc((size_t)DH * DL * 2);
    u16*   wd2t  = (u16*)alloc((size_t)DIN * DH * 2);
    float* cn2   = (float*)alloc((size_t)NE * 4);
    float* val8  = (float*)alloc((size_t)8 * B_ * 4);
    int*   idx8  = (int*)alloc((size_t)8 * B_ * 4);
    float* part  = (float*)alloc(64 * 4);

    // casts / transposes (weights -> [N][K] bf16)
    cast_bf16<<<(size_t)B_ * DIN / 1024, 256, 0, stream>>>(x, x_bf);
    cast_bf16<<<(size_t)NE * DL / 1024, 256, 0, stream>>>(cbk, cb_bf);
    transpose_cast<<<dim3(DH / 32, DIN / 32), 256, 0, stream>>>(ew1, w1t, DIN, DH);
    transpose_cast<<<dim3(DL / 32, DH / 32), 256, 0, stream>>>(ew2, w2t, DH, DL);
    transpose_cast<<<dim3(DH / 32, DL / 32), 256, 0, stream>>>(dw1, wd1t, DL, DH);
    transpose_cast<<<dim3(DIN / 32, DH / 32), 256, 0, stream>>>(dw2, wd2t, DH, DIN);
    cn2_kernel<<<NE / 4, 256, 0, stream>>>(cbk, cn2);

    // encoder
    gemm_big_bf16<1><<<(B_ / 256) * (DH / 128), 512, 0, stream>>>(
        x_bf, w1t, eb1, h_bf, B_, DH, DIN);
    gemm_bt_bf16<0><<<(B_ / 128) * (DL / 128), 256, 0, stream>>>(
        h_bf, w2t, eb2, z_bf, B_, DL, DH);

    // vector quantizer
    vq_score2<<<512, 256, 0, stream>>>(z_bf, cb_bf, cn2, val8, idx8);
    vq_select2<<<B_ / 256, 256, 0, stream>>>(val8, idx8, z_bf, cbk, zq_bf, part);
    loss_finalize<<<1, 256, 0, stream>>>(part, out + (size_t)B_ * DIN);

    // decoder
    gemm_big_bf16<1><<<(B_ / 256) * (DH / 128), 512, 0, stream>>>(
        zq_bf, wd1t, db1, h_bf, B_, DH, DL);
    gemm_big_bf16<2><<<(B_ / 256) * (DIN / 128), 512, 0, stream>>>(
        h_bf, wd2t, db2, out, B_, DIN, DH);
}

// Round 8
// 337.217 us; speedup vs baseline: 13.0403x; 1.0094x over previous
//
#include <hip/hip_runtime.h>
#include <math.h>

typedef unsigned short u16;
typedef __bf16 bf16x8 __attribute__((ext_vector_type(8)));
typedef float  f32x4  __attribute__((ext_vector_type(4)));

constexpr int B_  = 16384;   // batch
constexpr int DIN = 1024;    // input dim
constexpr int DH  = 2048;    // hidden dim
constexpr int DL  = 256;     // latent dim
constexpr int NE  = 8192;    // codebook entries

__device__ __forceinline__ u16 f2bf(float f) {     // RTNE float->bf16
    union { float f; unsigned u; } v; v.f = f;
    unsigned r = v.u + 0x7fffu + ((v.u >> 16) & 1u);
    return (u16)(r >> 16);
}
__device__ __forceinline__ float bf2f(u16 h) {
    union { unsigned u; float f; } v; v.u = ((unsigned)h) << 16;
    return v.f;
}

#define GLD16(gp, lp)                                                  \
    __builtin_amdgcn_global_load_lds(                                  \
        (__attribute__((address_space(1))) void*)(gp),                 \
        (__attribute__((address_space(3))) void*)(lp), 16, 0, 0)

#define SCHED0() __builtin_amdgcn_sched_barrier(0)
// raw barrier bracketed by sched_barrier(0): nothing (incl. reg-only MFMA,
// ds_read, GLD) may cross the barrier at compile time (rule #18 discipline)
#define BARRIER() do { SCHED0(); __builtin_amdgcn_s_barrier(); SCHED0(); } while (0)
#define WAITV0() asm volatile("s_waitcnt vmcnt(0)" ::: "memory")
#define WAITV3() asm volatile("s_waitcnt vmcnt(3)" ::: "memory")
#define WAITV4() asm volatile("s_waitcnt vmcnt(4)" ::: "memory")

// ---------------------------------------------------------------------------
// cast fp32 -> bf16, 4 elts/thread (n % 1024 == 0)
// ---------------------------------------------------------------------------
__global__ __launch_bounds__(256)
void cast_bf16(const float* __restrict__ in, u16* __restrict__ out)
{
    const size_t i = ((size_t)blockIdx.x * 256 + threadIdx.x) * 4;
    float4 v = *(const float4*)(in + i);
    ushort4 o;
    o.x = f2bf(v.x); o.y = f2bf(v.y); o.z = f2bf(v.z); o.w = f2bf(v.w);
    *(ushort4*)(out + i) = o;
}

// ---------------------------------------------------------------------------
// transpose-cast: in [R][C] fp32 -> out [C][R] bf16.  32x32 LDS tile.
// ---------------------------------------------------------------------------
__global__ __launch_bounds__(256)
void transpose_cast(const float* __restrict__ in, u16* __restrict__ out,
                    int R, int C)
{
    __shared__ float t[32][33];
    const int tx = threadIdx.x & 31, ty = threadIdx.x >> 5;
    const long bx = blockIdx.x;   // C/32
    const long by = blockIdx.y;   // R/32
#pragma unroll
    for (int p = 0; p < 4; ++p)
        t[ty + p * 8][tx] = in[(by * 32 + ty + p * 8) * (long)C + bx * 32 + tx];
    __syncthreads();
#pragma unroll
    for (int p = 0; p < 4; ++p)
        out[(bx * 32 + ty + p * 8) * (long)R + by * 32 + tx] = f2bf(t[tx][ty + p * 8]);
}

// ---------------------------------------------------------------------------
// cn2[k] = 0.5 * ||codebook[k]||^2 (fp32). One wave per code.
// ---------------------------------------------------------------------------
__global__ __launch_bounds__(256)
void cn2_kernel(const float* __restrict__ cb, float* __restrict__ cn2)
{
    const int code = (blockIdx.x * 256 + threadIdx.x) >> 6;
    const int lane = threadIdx.x & 63;
    float4 v = *(const float4*)(cb + (long)code * DL + lane * 4);
    float s = fmaf(v.x, v.x, fmaf(v.y, v.y, fmaf(v.z, v.z, v.w * v.w)));
#pragma unroll
    for (int off = 32; off; off >>= 1) s += __shfl_down(s, off);
    if (lane == 0) cn2[code] = 0.5f * s;
}

// ---------------------------------------------------------------------------
// BIG bf16 MFMA GEMM: BM=256, BN=128, BK=32, 512 threads = 8 waves (4M x 2N).
// T4 counted-vmcnt pipeline: 3 LDS buffers, prefetch depth 2, ONE raw
// s_barrier per K-step: { vmcnt(3) -> barrier -> stage(t+2) -> ds_read(t)
// + MFMA }. vmcnt never drained to 0 in the loop; loads get ~2 compute
// phases to land. Hazards: (1) reads of buf t gated by each wave's own
// vmcnt(3) + barrier; (2) stage(t+2) overwrites the buffer read at t-1 --
// all waves consumed those ds_reads (lgkm waits precede their MFMA, which
// precede barrier arrival). sched_barrier(0) brackets pin code motion.
// LDS XOR-swizzle (corrected key): source chunk (l&3)^((l>>3)&3), read
// chunk lg^((lm>>1)&3) -> 16-lane b128 reads = 2 lanes/bank-quad (free).
// K-accumulation order unchanged -> bitwise-same C. T1 XCD remap.
// EPI: 1 = bias+relu->bf16, 2 = bias+sigmoid->f32
// ---------------------------------------------------------------------------
template <int EPI>
__global__ __launch_bounds__(512, 4)
void gemm_big_bf16(const u16* __restrict__ A, const u16* __restrict__ Bt,
                   const float* __restrict__ bias, void* __restrict__ Cout,
                   int M, int N, int K)
{
    __shared__ __align__(16) u16 As[3 * 8192];   // 3 x 16 KB (256 rows x 32)
    __shared__ __align__(16) u16 Bs[3 * 4096];   // 3 x  8 KB (128 rows x 32)

    const int tid = threadIdx.x;
    const int w = tid >> 6, l = tid & 63;
    const int wm = w >> 1, wn = w & 1;

    // bijective XCD chunk-remap (nwg % 8 == 0 for all our shapes)
    const int nbx   = N >> 7;
    const int nwg   = (M >> 8) * nbx;
    const int chunk = nwg >> 3;
    const int wg    = ((int)blockIdx.x & 7) * chunk + ((int)blockIdx.x >> 3);
    const long by   = wg / nbx;
    const long bx   = wg % nbx;

    const int lr  = l >> 2;                      // row within 16-row segment
    const int lsw = (l & 3) ^ ((l >> 3) & 3);    // swizzled source chunk
    const int lg  = l >> 4, lm = l & 15;         // frag k-group / row index
    const int sx  = (lm >> 1) & 3;               // read-side xor key

    const u16* Abase = A  + (size_t)(by * 256) * K;
    const u16* Bbase = Bt + (size_t)(bx * 128) * K;

    f32x4 acc[4][4] = {};

    auto stage = [&](int k0, int b) {
        u16* dA = As + b * 8192;
        u16* dB = Bs + b * 4096;
#pragma unroll
        for (int i = 0; i < 2; ++i) {
            const int seg = w * 2 + i;           // 0..15 -> A rows seg*16..
            GLD16(Abase + (size_t)(seg * 16 + lr) * K + k0 + lsw * 8,
                  dA + seg * 512);
        }
        GLD16(Bbase + (size_t)(w * 16 + lr) * K + k0 + lsw * 8,
              dB + w * 512);
    };

    const int NT = K >> 5;                       // >= 8 for all our shapes
    stage(0, 0);
    stage(32, 1);

    int cur = 0, pre = 2;                        // t%3, (t+2)%3
    for (int t = 0; t < NT; ++t) {
        if (t + 1 < NT) { WAITV3(); } else { WAITV0(); }
        BARRIER();
        if (t + 2 < NT) stage((t + 2) << 5, pre);

        const u16* as = As + cur * 8192;
        const u16* bs = Bs + cur * 4096;
        bf16x8 af[4], bfr[4];
#pragma unroll
        for (int m = 0; m < 4; ++m) {
            const int R = wm * 64 + m * 16 + lm;
            af[m] = *(const bf16x8*)&as[R * 32 + ((lg ^ sx) * 8)];
        }
#pragma unroll
        for (int n = 0; n < 4; ++n) {
            const int R = wn * 64 + n * 16 + lm;
            bfr[n] = *(const bf16x8*)&bs[R * 32 + ((lg ^ sx) * 8)];
        }
#pragma unroll
        for (int m = 0; m < 4; ++m)
#pragma unroll
            for (int n = 0; n < 4; ++n)
                acc[m][n] = __builtin_amdgcn_mfma_f32_16x16x32_bf16(
                    af[m], bfr[n], acc[m][n], 0, 0, 0);

        cur = (cur == 2) ? 0 : cur + 1;
        pre = (pre == 2) ? 0 : pre + 1;
    }

    // epilogue: row = by*256+wm*64+m*16+lg*4+j, col = bx*128+wn*64+n*16+lm
#pragma unroll
    for (int n = 0; n < 4; ++n) {
        const long col = bx * 128 + wn * 64 + n * 16 + lm;
        const float bb = bias[col];
#pragma unroll
        for (int m = 0; m < 4; ++m) {
#pragma unroll
            for (int j = 0; j < 4; ++j) {
                const long row = by * 256 + wm * 64 + m * 16 + lg * 4 + j;
                float e = acc[m][n][j] + bb;
                if (EPI == 1) e = fmaxf(e, 0.f);
                if (EPI == 2) {
                    e = 1.f / (1.f + expf(-e));
                    ((float*)Cout)[row * (long)N + col] = e;
                } else {
                    ((u16*)Cout)[row * (long)N + col] = f2bf(e);
                }
            }
        }
    }
}

// ---------------------------------------------------------------------------
// 128^2 bf16 MFMA GEMM for GEMM2 (N=256). Same T4 counted-vmcnt structure
// (4 loads/stage -> steady wait vmcnt(4)), same corrected swizzle.
// EPI: 0 = bias->bf16
// ---------------------------------------------------------------------------
template <int EPI>
__global__ __launch_bounds__(256)
void gemm_bt_bf16(const u16* __restrict__ A, const u16* __restrict__ Bt,
                  const float* __restrict__ bias, void* __restrict__ Cout,
                  int M, int N, int K)
{
    __shared__ __align__(16) u16 As[3 * 4096];
    __shared__ __align__(16) u16 Bs[3 * 4096];

    const int tid = threadIdx.x;
    const int w = tid >> 6, l = tid & 63;
    const int wr = w >> 1, wc = w & 1;

    const int nbx   = N >> 7;
    const int nwg   = (M >> 7) * nbx;
    const int chunk = nwg >> 3;
    const int wg    = ((int)blockIdx.x & 7) * chunk + ((int)blockIdx.x >> 3);
    const long by   = wg / nbx;
    const long bx   = wg % nbx;

    const int lr  = l >> 2;
    const int lsw = (l & 3) ^ ((l >> 3) & 3);
    const int lg  = l >> 4, lm = l & 15;
    const int sx  = (lm >> 1) & 3;

    const u16* Abase = A  + (size_t)(by * 128) * K;
    const u16* Bbase = Bt + (size_t)(bx * 128) * K;

    f32x4 acc[4][4] = {};

    auto stage = [&](int k0, int b) {
        u16* dA = As + b * 4096;
        u16* dB = Bs + b * 4096;
#pragma unroll
        for (int i = 0; i < 2; ++i) {
            const int seg = w * 2 + i;
            GLD16(Abase + (size_t)(seg * 16 + lr) * K + k0 + lsw * 8, dA + seg * 512);
            GLD16(Bbase + (size_t)(seg * 16 + lr) * K + k0 + lsw * 8, dB + seg * 512);
        }
    };

    const int NT = K >> 5;
    stage(0, 0);
    stage(32, 1);

    int cur = 0, pre = 2;
    for (int t = 0; t < NT; ++t) {
        if (t + 1 < NT) { WAITV4(); } else { WAITV0(); }
        BARRIER();
        if (t + 2 < NT) stage((t + 2) << 5, pre);

        const u16* as = As + cur * 4096;
        const u16* bs = Bs + cur * 4096;
        bf16x8 af[4], bfr[4];
#pragma unroll
        for (int m = 0; m < 4; ++m)
            af[m] = *(const bf16x8*)&as[(wr * 64 + m * 16 + lm) * 32 + ((lg ^ sx) * 8)];
#pragma unroll
        for (int n = 0; n < 4; ++n)
            bfr[n] = *(const bf16x8*)&bs[(wc * 64 + n * 16 + lm) * 32 + ((lg ^ sx) * 8)];
#pragma unroll
        for (int m = 0; m < 4; ++m)
#pragma unroll
            for (int n = 0; n < 4; ++n)
                acc[m][n] = __builtin_amdgcn_mfma_f32_16x16x32_bf16(
                    af[m], bfr[n], acc[m][n], 0, 0, 0);

        cur = (cur == 2) ? 0 : cur + 1;
        pre = (pre == 2) ? 0 : pre + 1;
    }

#pragma unroll
    for (int n = 0; n < 4; ++n) {
        const long col = bx * 128 + wc * 64 + n * 16 + lm;
        const float bb = bias[col];
#pragma unroll
        for (int m = 0; m < 4; ++m) {
#pragma unroll
            for (int j = 0; j < 4; ++j) {
                const long row = by * 128 + wr * 64 + m * 16 + lg * 4 + j;
                float e = acc[m][n][j] + bb;
                if (EPI == 1) e = fmaxf(e, 0.f);
                if (EPI == 2) {
                    e = 1.f / (1.f + expf(-e));
                    ((float*)Cout)[row * (long)N + col] = e;
                } else {
                    ((u16*)Cout)[row * (long)N + col] = f2bf(e);
                }
            }
        }
    }
}

// ---------------------------------------------------------------------------
// VQ phase 1 v2: register-resident A, LDS-streamed codebook (unchanged;
// its barrier drain is covered by the ~512-MFMA compute phase).
// ---------------------------------------------------------------------------
__global__ __launch_bounds__(256, 2)
void vq_score2(const u16* __restrict__ z, const u16* __restrict__ cbt,
               const float* __restrict__ cn2,
               float* __restrict__ val8, int* __restrict__ idx8)
{
    __shared__ __align__(16) u16 lds[32768];

    const int tid = threadIdx.x;
    const int w = tid >> 6, l = tid & 63;
    const int rq = blockIdx.x >> 3;
    const int q  = blockIdx.x & 7;

    const int st_row8 = tid >> 5;
    const int st_s    = (tid & 31) ^ st_row8;
    const int lg = l >> 4, lm = l & 15;
    const int swz_x = l & 7;

    bf16x8 af[4][8];
    const long zbase_row = (long)rq * 256;
#pragma unroll
    for (int h = 0; h < 2; ++h) {
#pragma unroll
        for (int i = 0; i < 16; ++i) {
            const int row = i * 8 + st_row8;
            const u16* g = z + (zbase_row + h * 128 + row) * DL + st_s * 8;
            GLD16(g, lds + ((size_t)i * 256 + w * 64) * 8);
        }
        __syncthreads();
        if ((w >> 1) == h) {
            const int lrow0 = (w & 1) * 64;
#pragma unroll
            for (int m = 0; m < 4; ++m) {
                const int lrow = lrow0 + m * 16 + lm;
#pragma unroll
                for (int kg = 0; kg < 8; ++kg) {
                    const int s = (kg * 4 + lg) ^ swz_x;
                    af[m][kg] = *(const bf16x8*)&lds[lrow * 256 + s * 8];
                }
            }
        }
        __syncthreads();
    }

    const int code00 = q * (NE / 8);

    float bestv[16];
    int   besti[16];
#pragma unroll
    for (int k = 0; k < 16; ++k) { bestv[k] = 1e30f; besti[k] = 0; }

    auto stage_tile = [&](int t) {
        const int b = t & 1;
#pragma unroll
        for (int i = 0; i < 8; ++i) {
            const int c = i * 8 + st_row8;
            const u16* g = cbt + (size_t)(code00 + t * 64 + c) * DL + st_s * 8;
            GLD16(g, lds + ((size_t)b * 16384 + ((size_t)i * 256 + w * 64) * 8));
        }
    };

    stage_tile(0);
    __syncthreads();

    for (int t = 0; t < 16; ++t) {
        if (t < 15) stage_tile(t + 1);
        const u16* buf = lds + (size_t)(t & 1) * 16384;

#pragma unroll
        for (int n = 0; n < 4; ++n) {
            const int code_g = code00 + t * 64 + n * 16 + lm;
            const float cn2v = cn2[code_g];
            bf16x8 bfr[8];
#pragma unroll
            for (int kg = 0; kg < 8; ++kg) {
                const int lrow = n * 16 + lm;
                const int s = (kg * 4 + lg) ^ swz_x;
                bfr[kg] = *(const bf16x8*)&buf[lrow * 256 + s * 8];
            }
            f32x4 acc[4] = {};
#pragma unroll
            for (int kg = 0; kg < 8; ++kg)
#pragma unroll
                for (int m = 0; m < 4; ++m)
                    acc[m] = __builtin_amdgcn_mfma_f32_16x16x32_bf16(
                        af[m][kg], bfr[kg], acc[m], 0, 0, 0);
#pragma unroll
            for (int m = 0; m < 4; ++m)
#pragma unroll
                for (int j = 0; j < 4; ++j) {
                    const float s = cn2v - acc[m][j];
                    const int k16 = m * 4 + j;
                    if (s < bestv[k16]) { bestv[k16] = s; besti[k16] = code_g; }
                }
        }
        __syncthreads();
    }

#pragma unroll
    for (int off = 1; off < 16; off <<= 1) {
#pragma unroll
        for (int k = 0; k < 16; ++k) {
            const float ov = __shfl_xor(bestv[k], off);
            const int   oi = __shfl_xor(besti[k], off);
            if (ov < bestv[k] || (ov == bestv[k] && oi < besti[k])) {
                bestv[k] = ov; besti[k] = oi;
            }
        }
    }
    if (lm == 0) {
#pragma unroll
        for (int m = 0; m < 4; ++m)
#pragma unroll
            for (int j = 0; j < 4; ++j) {
                const long row = zbase_row + w * 64 + m * 16 + lg * 4 + j;
                val8[(size_t)q * B_ + row] = bestv[m * 4 + j];
                idx8[(size_t)q * B_ + row] = besti[m * 4 + j];
            }
    }
}

// ---------------------------------------------------------------------------
// VQ phase 2: per row pick best of 8 candidates, gather z_q, loss partials.
// ---------------------------------------------------------------------------
__global__ __launch_bounds__(256)
void vq_select2(const float* __restrict__ val8, const int* __restrict__ idx8,
                const u16* __restrict__ z, const float* __restrict__ cb,
                u16* __restrict__ zq, float* __restrict__ partial)
{
    __shared__ int   s_idx[256];
    __shared__ float s_red[4];
    const int tid = threadIdx.x;
    const long row = (long)blockIdx.x * 256 + tid;

    float bv = val8[row];
    int   bi = idx8[row];
#pragma unroll
    for (int qq = 1; qq < 8; ++qq) {
        const float v = val8[(size_t)qq * B_ + row];
        const int   i = idx8[(size_t)qq * B_ + row];
        if (v < bv || (v == bv && i < bi)) { bv = v; bi = i; }
    }
    s_idx[tid] = bi;
    __syncthreads();

    float ls = 0.f;
    const int sub = tid & 7;
#pragma unroll
    for (int pass = 0; pass < 8; ++pass) {
        const int rl = pass * 32 + (tid >> 3);
        const int gi = s_idx[rl];
        const long rg = (long)blockIdx.x * 256 + rl;
#pragma unroll
        for (int tt = 0; tt < 8; ++tt) {
            const int d = sub * 4 + tt * 32;
            float4 c4 = *(const float4*)(cb + (long)gi * DL + d);
            ushort4 zu = *(const ushort4*)(z + rg * DL + d);
            ushort4 qo;
            qo.x = f2bf(c4.x); qo.y = f2bf(c4.y);
            qo.z = f2bf(c4.z); qo.w = f2bf(c4.w);
            *(ushort4*)(zq + rg * DL + d) = qo;
            const float dx = c4.x - bf2f(zu.x), dy = c4.y - bf2f(zu.y);
            const float dz = c4.z - bf2f(zu.z), dw = c4.w - bf2f(zu.w);
            ls += dx * dx + dy * dy + dz * dz + dw * dw;
        }
    }
#pragma unroll
    for (int off = 32; off; off >>= 1) ls += __shfl_down(ls, off);
    if ((tid & 63) == 0) s_red[tid >> 6] = ls;
    __syncthreads();
    if (tid == 0)
        partial[blockIdx.x] = s_red[0] + s_red[1] + s_red[2] + s_red[3];
}

// ---------------------------------------------------------------------------
// loss = 1.25 * sum(partial[64]) / (B_*DL)
// ---------------------------------------------------------------------------
__global__ __launch_bounds__(256)
void loss_finalize(const float* __restrict__ partial, float* __restrict__ out)
{
    __shared__ float s_red[4];
    const int tid = threadIdx.x;
    float s = (tid < 64) ? partial[tid] : 0.f;
#pragma unroll
    for (int off = 32; off; off >>= 1) s += __shfl_down(s, off);
    if ((tid & 63) == 0) s_red[tid >> 6] = s;
    __syncthreads();
    if (tid == 0)
        out[0] = 1.25f * (s_red[0] + s_red[1] + s_red[2] + s_red[3])
                 / (float)((long)B_ * DL);
}

// ---------------------------------------------------------------------------
extern "C" void kernel_launch(void* const* d_in, const int* in_sizes, int n_in,
                              void* d_out, int out_size, void* d_ws, size_t ws_size,
                              hipStream_t stream)
{
    const float* x   = (const float*)d_in[0];
    const float* ew1 = (const float*)d_in[1];
    const float* eb1 = (const float*)d_in[2];
    const float* ew2 = (const float*)d_in[3];
    const float* eb2 = (const float*)d_in[4];
    const float* cbk = (const float*)d_in[5];
    const float* dw1 = (const float*)d_in[6];
    const float* db1 = (const float*)d_in[7];
    const float* dw2 = (const float*)d_in[8];
    const float* db2 = (const float*)d_in[9];
    float* out = (float*)d_out;

    char* p = (char*)d_ws;
    auto alloc = [&](size_t bytes) {
        char* r = p; p += (bytes + 255) & ~(size_t)255; return r;
    };
    u16*   x_bf  = (u16*)alloc((size_t)B_ * DIN * 2);
    u16*   h_bf  = (u16*)alloc((size_t)B_ * DH * 2);   // also decoder hidden
    u16*   z_bf  = (u16*)alloc((size_t)B_ * DL * 2);
    u16*   zq_bf = (u16*)alloc((size_t)B_ * DL * 2);
    u16*   cb_bf = (u16*)alloc((size_t)NE * DL * 2);
    u16*   w1t   = (u16*)alloc((size_t)DH * DIN * 2);  // [N][K] bf16
    u16*   w2t   = (u16*)alloc((size_t)DL * DH * 2);
    u16*   wd1t  = (u16*)alloc((size_t)DH * DL * 2);
    u16*   wd2t  = (u16*)alloc((size_t)DIN * DH * 2);
    float* cn2   = (float*)alloc((size_t)NE * 4);
    float* val8  = (float*)alloc((size_t)8 * B_ * 4);
    int*   idx8  = (int*)alloc((size_t)8 * B_ * 4);
    float* part  = (float*)alloc(64 * 4);

    // casts / transposes (weights -> [N][K] bf16)
    cast_bf16<<<(size_t)B_ * DIN / 1024, 256, 0, stream>>>(x, x_bf);
    cast_bf16<<<(size_t)NE * DL / 1024, 256, 0, stream>>>(cbk, cb_bf);
    transpose_cast<<<dim3(DH / 32, DIN / 32), 256, 0, stream>>>(ew1, w1t, DIN, DH);
    transpose_cast<<<dim3(DL / 32, DH / 32), 256, 0, stream>>>(ew2, w2t, DH, DL);
    transpose_cast<<<dim3(DH / 32, DL / 32), 256, 0, stream>>>(dw1, wd1t, DL, DH);
    transpose_cast<<<dim3(DIN / 32, DH / 32), 256, 0, stream>>>(dw2, wd2t, DH, DIN);
    cn2_kernel<<<NE / 4, 256, 0, stream>>>(cbk, cn2);

    // encoder
    gemm_big_bf16<1><<<(B_ / 256) * (DH / 128), 512, 0, stream>>>(
        x_bf, w1t, eb1, h_bf, B_, DH, DIN);
    gemm_bt_bf16<0><<<(B_ / 128) * (DL / 128), 256, 0, stream>>>(
        h_bf, w2t, eb2, z_bf, B_, DL, DH);

    // vector quantizer
    vq_score2<<<512, 256, 0, stream>>>(z_bf, cb_bf, cn2, val8, idx8);
    vq_select2<<<B_ / 256, 256, 0, stream>>>(val8, idx8, z_bf, cbk, zq_bf, part);
    loss_finalize<<<1, 256, 0, stream>>>(part, out + (size_t)B_ * DIN);

    // decoder
    gemm_big_bf16<1><<<(B_ / 256) * (DH / 128), 512, 0, stream>>>(
        zq_bf, wd1t, db1, h_bf, B_, DH, DL);
    gemm_big_bf16<2><<<(B_ / 256) * (DIN / 128), 512, 0, stream>>>(
        h_bf, wd2t, db2, out, B_, DIN, DH);
}

// Round 9
// 324.694 us; speedup vs baseline: 13.5432x; 1.0386x over previous
//
#include <hip/hip_runtime.h>
#include <math.h>

typedef unsigned short u16;
typedef __bf16 bf16x8 __attribute__((ext_vector_type(8)));
typedef float  f32x4  __attribute__((ext_vector_type(4)));

constexpr int B_  = 16384;   // batch
constexpr int DIN = 1024;    // input dim
constexpr int DH  = 2048;    // hidden dim
constexpr int DL  = 256;     // latent dim
constexpr int NE  = 8192;    // codebook entries

__device__ __forceinline__ u16 f2bf(float f) {     // RTNE float->bf16
    union { float f; unsigned u; } v; v.f = f;
    unsigned r = v.u + 0x7fffu + ((v.u >> 16) & 1u);
    return (u16)(r >> 16);
}
__device__ __forceinline__ float bf2f(u16 h) {
    union { unsigned u; float f; } v; v.u = ((unsigned)h) << 16;
    return v.f;
}

#define GLD16(gp, lp)                                                  \
    __builtin_amdgcn_global_load_lds(                                  \
        (__attribute__((address_space(1))) void*)(gp),                 \
        (__attribute__((address_space(3))) void*)(lp), 16, 0, 0)

#define SCHED0() __builtin_amdgcn_sched_barrier(0)
#define BARRIER() do { SCHED0(); __builtin_amdgcn_s_barrier(); SCHED0(); } while (0)
#define WAITV0() asm volatile("s_waitcnt vmcnt(0)" ::: "memory")
#define WAITV3() asm volatile("s_waitcnt vmcnt(3)" ::: "memory")
#define WAITV4() asm volatile("s_waitcnt vmcnt(4)" ::: "memory")

// ---------------------------------------------------------------------------
// cast fp32 -> bf16, 4 elts/thread (n % 1024 == 0)
// ---------------------------------------------------------------------------
__global__ __launch_bounds__(256)
void cast_bf16(const float* __restrict__ in, u16* __restrict__ out)
{
    const size_t i = ((size_t)blockIdx.x * 256 + threadIdx.x) * 4;
    float4 v = *(const float4*)(in + i);
    ushort4 o;
    o.x = f2bf(v.x); o.y = f2bf(v.y); o.z = f2bf(v.z); o.w = f2bf(v.w);
    *(ushort4*)(out + i) = o;
}

// ---------------------------------------------------------------------------
// transpose-cast: in [R][C] fp32 -> out [C][R] bf16.  32x32 LDS tile.
// ---------------------------------------------------------------------------
__global__ __launch_bounds__(256)
void transpose_cast(const float* __restrict__ in, u16* __restrict__ out,
                    int R, int C)
{
    __shared__ float t[32][33];
    const int tx = threadIdx.x & 31, ty = threadIdx.x >> 5;
    const long bx = blockIdx.x;   // C/32
    const long by = blockIdx.y;   // R/32
#pragma unroll
    for (int p = 0; p < 4; ++p)
        t[ty + p * 8][tx] = in[(by * 32 + ty + p * 8) * (long)C + bx * 32 + tx];
    __syncthreads();
#pragma unroll
    for (int p = 0; p < 4; ++p)
        out[(bx * 32 + ty + p * 8) * (long)R + by * 32 + tx] = f2bf(t[tx][ty + p * 8]);
}

// ---------------------------------------------------------------------------
// cn2[k] = 0.5 * ||codebook[k]||^2 (fp32). One wave per code.
// ---------------------------------------------------------------------------
__global__ __launch_bounds__(256)
void cn2_kernel(const float* __restrict__ cb, float* __restrict__ cn2)
{
    const int code = (blockIdx.x * 256 + threadIdx.x) >> 6;
    const int lane = threadIdx.x & 63;
    float4 v = *(const float4*)(cb + (long)code * DL + lane * 4);
    float s = fmaf(v.x, v.x, fmaf(v.y, v.y, fmaf(v.z, v.z, v.w * v.w)));
#pragma unroll
    for (int off = 32; off; off >>= 1) s += __shfl_down(s, off);
    if (lane == 0) cn2[code] = 0.5f * s;
}

// ---------------------------------------------------------------------------
// BIG bf16 MFMA GEMM: BM=256, BN=128, BK=32, 512 threads = 8 waves (4M x 2N).
// T4 counted-vmcnt pipeline, 3 LDS buffers, one raw s_barrier per K-step.
// LDS XOR-swizzle both-sides. T1 XCD remap (nwg % 8 == 0 required).
// K-accumulation order fixed (kg ascending) -> per-row results are
// M-independent and bitwise-stable across launch shapes.
// EPI: 1 = bias+relu->bf16, 2 = bias+sigmoid->f32
// ---------------------------------------------------------------------------
template <int EPI>
__global__ __launch_bounds__(512, 4)
void gemm_big_bf16(const u16* __restrict__ A, const u16* __restrict__ Bt,
                   const float* __restrict__ bias, void* __restrict__ Cout,
                   int M, int N, int K)
{
    __shared__ __align__(16) u16 As[3 * 8192];   // 3 x 16 KB (256 rows x 32)
    __shared__ __align__(16) u16 Bs[3 * 4096];   // 3 x  8 KB (128 rows x 32)

    const int tid = threadIdx.x;
    const int w = tid >> 6, l = tid & 63;
    const int wm = w >> 1, wn = w & 1;

    const int nbx   = N >> 7;
    const int nwg   = (M >> 8) * nbx;
    const int chunk = nwg >> 3;
    const int wg    = ((int)blockIdx.x & 7) * chunk + ((int)blockIdx.x >> 3);
    const long by   = wg / nbx;
    const long bx   = wg % nbx;

    const int lr  = l >> 2;                      // row within 16-row segment
    const int lsw = (l & 3) ^ ((l >> 3) & 3);    // swizzled source chunk
    const int lg  = l >> 4, lm = l & 15;         // frag k-group / row index
    const int sx  = (lm >> 1) & 3;               // read-side xor key

    const u16* Abase = A  + (size_t)(by * 256) * K;
    const u16* Bbase = Bt + (size_t)(bx * 128) * K;

    f32x4 acc[4][4] = {};

    auto stage = [&](int k0, int b) {
        u16* dA = As + b * 8192;
        u16* dB = Bs + b * 4096;
#pragma unroll
        for (int i = 0; i < 2; ++i) {
            const int seg = w * 2 + i;           // 0..15 -> A rows seg*16..
            GLD16(Abase + (size_t)(seg * 16 + lr) * K + k0 + lsw * 8,
                  dA + seg * 512);
        }
        GLD16(Bbase + (size_t)(w * 16 + lr) * K + k0 + lsw * 8,
              dB + w * 512);
    };

    const int NT = K >> 5;
    stage(0, 0);
    stage(32, 1);

    int cur = 0, pre = 2;
    for (int t = 0; t < NT; ++t) {
        if (t + 1 < NT) { WAITV3(); } else { WAITV0(); }
        BARRIER();
        if (t + 2 < NT) stage((t + 2) << 5, pre);

        const u16* as = As + cur * 8192;
        const u16* bs = Bs + cur * 4096;
        bf16x8 af[4], bfr[4];
#pragma unroll
        for (int m = 0; m < 4; ++m) {
            const int R = wm * 64 + m * 16 + lm;
            af[m] = *(const bf16x8*)&as[R * 32 + ((lg ^ sx) * 8)];
        }
#pragma unroll
        for (int n = 0; n < 4; ++n) {
            const int R = wn * 64 + n * 16 + lm;
            bfr[n] = *(const bf16x8*)&bs[R * 32 + ((lg ^ sx) * 8)];
        }
#pragma unroll
        for (int m = 0; m < 4; ++m)
#pragma unroll
            for (int n = 0; n < 4; ++n)
                acc[m][n] = __builtin_amdgcn_mfma_f32_16x16x32_bf16(
                    af[m], bfr[n], acc[m][n], 0, 0, 0);

        cur = (cur == 2) ? 0 : cur + 1;
        pre = (pre == 2) ? 0 : pre + 1;
    }

#pragma unroll
    for (int n = 0; n < 4; ++n) {
        const long col = bx * 128 + wn * 64 + n * 16 + lm;
        const float bb = bias[col];
#pragma unroll
        for (int m = 0; m < 4; ++m) {
#pragma unroll
            for (int j = 0; j < 4; ++j) {
                const long row = by * 256 + wm * 64 + m * 16 + lg * 4 + j;
                float e = acc[m][n][j] + bb;
                if (EPI == 1) e = fmaxf(e, 0.f);
                if (EPI == 2) {
                    e = 1.f / (1.f + expf(-e));
                    ((float*)Cout)[row * (long)N + col] = e;
                } else {
                    ((u16*)Cout)[row * (long)N + col] = f2bf(e);
                }
            }
        }
    }
}

// ---------------------------------------------------------------------------
// 128^2 bf16 MFMA GEMM for GEMM2 (N=256). T4 counted-vmcnt, swizzled.
// EPI: 0 = bias->bf16
// ---------------------------------------------------------------------------
template <int EPI>
__global__ __launch_bounds__(256)
void gemm_bt_bf16(const u16* __restrict__ A, const u16* __restrict__ Bt,
                  const float* __restrict__ bias, void* __restrict__ Cout,
                  int M, int N, int K)
{
    __shared__ __align__(16) u16 As[3 * 4096];
    __shared__ __align__(16) u16 Bs[3 * 4096];

    const int tid = threadIdx.x;
    const int w = tid >> 6, l = tid & 63;
    const int wr = w >> 1, wc = w & 1;

    const int nbx   = N >> 7;
    const int nwg   = (M >> 7) * nbx;
    const int chunk = nwg >> 3;
    const int wg    = ((int)blockIdx.x & 7) * chunk + ((int)blockIdx.x >> 3);
    const long by   = wg / nbx;
    const long bx   = wg % nbx;

    const int lr  = l >> 2;
    const int lsw = (l & 3) ^ ((l >> 3) & 3);
    const int lg  = l >> 4, lm = l & 15;
    const int sx  = (lm >> 1) & 3;

    const u16* Abase = A  + (size_t)(by * 128) * K;
    const u16* Bbase = Bt + (size_t)(bx * 128) * K;

    f32x4 acc[4][4] = {};

    auto stage = [&](int k0, int b) {
        u16* dA = As + b * 4096;
        u16* dB = Bs + b * 4096;
#pragma unroll
        for (int i = 0; i < 2; ++i) {
            const int seg = w * 2 + i;
            GLD16(Abase + (size_t)(seg * 16 + lr) * K + k0 + lsw * 8, dA + seg * 512);
            GLD16(Bbase + (size_t)(seg * 16 + lr) * K + k0 + lsw * 8, dB + seg * 512);
        }
    };

    const int NT = K >> 5;
    stage(0, 0);
    stage(32, 1);

    int cur = 0, pre = 2;
    for (int t = 0; t < NT; ++t) {
        if (t + 1 < NT) { WAITV4(); } else { WAITV0(); }
        BARRIER();
        if (t + 2 < NT) stage((t + 2) << 5, pre);

        const u16* as = As + cur * 4096;
        const u16* bs = Bs + cur * 4096;
        bf16x8 af[4], bfr[4];
#pragma unroll
        for (int m = 0; m < 4; ++m)
            af[m] = *(const bf16x8*)&as[(wr * 64 + m * 16 + lm) * 32 + ((lg ^ sx) * 8)];
#pragma unroll
        for (int n = 0; n < 4; ++n)
            bfr[n] = *(const bf16x8*)&bs[(wc * 64 + n * 16 + lm) * 32 + ((lg ^ sx) * 8)];
#pragma unroll
        for (int m = 0; m < 4; ++m)
#pragma unroll
            for (int n = 0; n < 4; ++n)
                acc[m][n] = __builtin_amdgcn_mfma_f32_16x16x32_bf16(
                    af[m], bfr[n], acc[m][n], 0, 0, 0);

        cur = (cur == 2) ? 0 : cur + 1;
        pre = (pre == 2) ? 0 : pre + 1;
    }

#pragma unroll
    for (int n = 0; n < 4; ++n) {
        const long col = bx * 128 + wc * 64 + n * 16 + lm;
        const float bb = bias[col];
#pragma unroll
        for (int m = 0; m < 4; ++m) {
#pragma unroll
            for (int j = 0; j < 4; ++j) {
                const long row = by * 128 + wr * 64 + m * 16 + lg * 4 + j;
                float e = acc[m][n][j] + bb;
                if (EPI == 1) e = fmaxf(e, 0.f);
                if (EPI == 2) {
                    e = 1.f / (1.f + expf(-e));
                    ((float*)Cout)[row * (long)N + col] = e;
                } else {
                    ((u16*)Cout)[row * (long)N + col] = f2bf(e);
                }
            }
        }
    }
}

// ---------------------------------------------------------------------------
// VQ phase 1 v2: register-resident A, LDS-streamed codebook (unchanged).
// ---------------------------------------------------------------------------
__global__ __launch_bounds__(256, 2)
void vq_score2(const u16* __restrict__ z, const u16* __restrict__ cbt,
               const float* __restrict__ cn2,
               float* __restrict__ val8, int* __restrict__ idx8)
{
    __shared__ __align__(16) u16 lds[32768];

    const int tid = threadIdx.x;
    const int w = tid >> 6, l = tid & 63;
    const int rq = blockIdx.x >> 3;
    const int q  = blockIdx.x & 7;

    const int st_row8 = tid >> 5;
    const int st_s    = (tid & 31) ^ st_row8;
    const int lg = l >> 4, lm = l & 15;
    const int swz_x = l & 7;

    bf16x8 af[4][8];
    const long zbase_row = (long)rq * 256;
#pragma unroll
    for (int h = 0; h < 2; ++h) {
#pragma unroll
        for (int i = 0; i < 16; ++i) {
            const int row = i * 8 + st_row8;
            const u16* g = z + (zbase_row + h * 128 + row) * DL + st_s * 8;
            GLD16(g, lds + ((size_t)i * 256 + w * 64) * 8);
        }
        __syncthreads();
        if ((w >> 1) == h) {
            const int lrow0 = (w & 1) * 64;
#pragma unroll
            for (int m = 0; m < 4; ++m) {
                const int lrow = lrow0 + m * 16 + lm;
#pragma unroll
                for (int kg = 0; kg < 8; ++kg) {
                    const int s = (kg * 4 + lg) ^ swz_x;
                    af[m][kg] = *(const bf16x8*)&lds[lrow * 256 + s * 8];
                }
            }
        }
        __syncthreads();
    }

    const int code00 = q * (NE / 8);

    float bestv[16];
    int   besti[16];
#pragma unroll
    for (int k = 0; k < 16; ++k) { bestv[k] = 1e30f; besti[k] = 0; }

    auto stage_tile = [&](int t) {
        const int b = t & 1;
#pragma unroll
        for (int i = 0; i < 8; ++i) {
            const int c = i * 8 + st_row8;
            const u16* g = cbt + (size_t)(code00 + t * 64 + c) * DL + st_s * 8;
            GLD16(g, lds + ((size_t)b * 16384 + ((size_t)i * 256 + w * 64) * 8));
        }
    };

    stage_tile(0);
    __syncthreads();

    for (int t = 0; t < 16; ++t) {
        if (t < 15) stage_tile(t + 1);
        const u16* buf = lds + (size_t)(t & 1) * 16384;

#pragma unroll
        for (int n = 0; n < 4; ++n) {
            const int code_g = code00 + t * 64 + n * 16 + lm;
            const float cn2v = cn2[code_g];
            bf16x8 bfr[8];
#pragma unroll
            for (int kg = 0; kg < 8; ++kg) {
                const int lrow = n * 16 + lm;
                const int s = (kg * 4 + lg) ^ swz_x;
                bfr[kg] = *(const bf16x8*)&buf[lrow * 256 + s * 8];
            }
            f32x4 acc[4] = {};
#pragma unroll
            for (int kg = 0; kg < 8; ++kg)
#pragma unroll
                for (int m = 0; m < 4; ++m)
                    acc[m] = __builtin_amdgcn_mfma_f32_16x16x32_bf16(
                        af[m][kg], bfr[kg], acc[m], 0, 0, 0);
#pragma unroll
            for (int m = 0; m < 4; ++m)
#pragma unroll
                for (int j = 0; j < 4; ++j) {
                    const float s = cn2v - acc[m][j];
                    const int k16 = m * 4 + j;
                    if (s < bestv[k16]) { bestv[k16] = s; besti[k16] = code_g; }
                }
        }
        __syncthreads();
    }

#pragma unroll
    for (int off = 1; off < 16; off <<= 1) {
#pragma unroll
        for (int k = 0; k < 16; ++k) {
            const float ov = __shfl_xor(bestv[k], off);
            const int   oi = __shfl_xor(besti[k], off);
            if (ov < bestv[k] || (ov == bestv[k] && oi < besti[k])) {
                bestv[k] = ov; besti[k] = oi;
            }
        }
    }
    if (lm == 0) {
#pragma unroll
        for (int m = 0; m < 4; ++m)
#pragma unroll
            for (int j = 0; j < 4; ++j) {
                const long row = zbase_row + w * 64 + m * 16 + lg * 4 + j;
                val8[(size_t)q * B_ + row] = bestv[m * 4 + j];
                idx8[(size_t)q * B_ + row] = besti[m * 4 + j];
            }
    }
}

// ---------------------------------------------------------------------------
// VQ phase 2: per row pick best of 8 candidates (tie-break lowest idx),
// write final index, accumulate loss partial. No z_q materialization --
// the decoder now runs per-code, not per-row.
// ---------------------------------------------------------------------------
__global__ __launch_bounds__(256)
void vq_select2(const float* __restrict__ val8, const int* __restrict__ idx8,
                const u16* __restrict__ z, const float* __restrict__ cb,
                int* __restrict__ idxf, float* __restrict__ partial)
{
    __shared__ int   s_idx[256];
    __shared__ float s_red[4];
    const int tid = threadIdx.x;
    const long row = (long)blockIdx.x * 256 + tid;

    float bv = val8[row];
    int   bi = idx8[row];
#pragma unroll
    for (int qq = 1; qq < 8; ++qq) {
        const float v = val8[(size_t)qq * B_ + row];
        const int   i = idx8[(size_t)qq * B_ + row];
        if (v < bv || (v == bv && i < bi)) { bv = v; bi = i; }
    }
    s_idx[tid] = bi;
    idxf[row]  = bi;
    __syncthreads();

    float ls = 0.f;
    const int sub = tid & 7;
#pragma unroll
    for (int pass = 0; pass < 8; ++pass) {
        const int rl = pass * 32 + (tid >> 3);
        const int gi = s_idx[rl];
        const long rg = (long)blockIdx.x * 256 + rl;
#pragma unroll
        for (int tt = 0; tt < 8; ++tt) {
            const int d = sub * 4 + tt * 32;
            float4 c4 = *(const float4*)(cb + (long)gi * DL + d);
            ushort4 zu = *(const ushort4*)(z + rg * DL + d);
            const float dx = c4.x - bf2f(zu.x), dy = c4.y - bf2f(zu.y);
            const float dz = c4.z - bf2f(zu.z), dw = c4.w - bf2f(zu.w);
            ls += dx * dx + dy * dy + dz * dz + dw * dw;
        }
    }
#pragma unroll
    for (int off = 32; off; off >>= 1) ls += __shfl_down(ls, off);
    if ((tid & 63) == 0) s_red[tid >> 6] = ls;
    __syncthreads();
    if (tid == 0)
        partial[blockIdx.x] = s_red[0] + s_red[1] + s_red[2] + s_red[3];
}

// ---------------------------------------------------------------------------
// loss = 1.25 * sum(partial[64]) / (B_*DL)
// ---------------------------------------------------------------------------
__global__ __launch_bounds__(256)
void loss_finalize(const float* __restrict__ partial, float* __restrict__ out)
{
    __shared__ float s_red[4];
    const int tid = threadIdx.x;
    float s = (tid < 64) ? partial[tid] : 0.f;
#pragma unroll
    for (int off = 32; off; off >>= 1) s += __shfl_down(s, off);
    if ((tid & 63) == 0) s_red[tid >> 6] = s;
    __syncthreads();
    if (tid == 0)
        out[0] = 1.25f * (s_red[0] + s_red[1] + s_red[2] + s_red[3])
                 / (float)((long)B_ * DL);
}

// ---------------------------------------------------------------------------
// gather: out[row] = Xcode[idxf[row]]  (1024 f32/row; one wave per row).
// Xcode (33.5 MB) is L3-resident; write-bound at ~67 MB.
// ---------------------------------------------------------------------------
__global__ __launch_bounds__(256)
void gather_rows(const float* __restrict__ Xcode, const int* __restrict__ idxf,
                 float* __restrict__ out)
{
    const int tid  = threadIdx.x;
    const int lane = tid & 63;
    const long row = (long)blockIdx.x * 4 + (tid >> 6);
    const long gi  = idxf[row];
    const float* src = Xcode + gi * DIN;
    float*       dst = out + row * DIN;
#pragma unroll
    for (int t = 0; t < 4; ++t) {
        const int d = lane * 4 + t * 256;
        *(float4*)(dst + d) = *(const float4*)(src + d);
    }
}

// ---------------------------------------------------------------------------
extern "C" void kernel_launch(void* const* d_in, const int* in_sizes, int n_in,
                              void* d_out, int out_size, void* d_ws, size_t ws_size,
                              hipStream_t stream)
{
    const float* x   = (const float*)d_in[0];
    const float* ew1 = (const float*)d_in[1];
    const float* eb1 = (const float*)d_in[2];
    const float* ew2 = (const float*)d_in[3];
    const float* eb2 = (const float*)d_in[4];
    const float* cbk = (const float*)d_in[5];
    const float* dw1 = (const float*)d_in[6];
    const float* db1 = (const float*)d_in[7];
    const float* dw2 = (const float*)d_in[8];
    const float* db2 = (const float*)d_in[9];
    float* out = (float*)d_out;

    char* p = (char*)d_ws;
    auto alloc = [&](size_t bytes) {
        char* r = p; p += (bytes + 255) & ~(size_t)255; return r;
    };
    u16*   x_bf  = (u16*)alloc((size_t)B_ * DIN * 2);
    u16*   h_bf  = (u16*)alloc((size_t)B_ * DH * 2);   // encoder h; then Hcode
    u16*   z_bf  = (u16*)alloc((size_t)B_ * DL * 2);
    u16*   cb_bf = (u16*)alloc((size_t)NE * DL * 2);
    u16*   w1t   = (u16*)alloc((size_t)DH * DIN * 2);  // [N][K] bf16
    u16*   w2t   = (u16*)alloc((size_t)DL * DH * 2);
    u16*   wd1t  = (u16*)alloc((size_t)DH * DL * 2);
    u16*   wd2t  = (u16*)alloc((size_t)DIN * DH * 2);
    float* Xcode = (float*)alloc((size_t)NE * DIN * 4);   // per-code recon
    float* cn2   = (float*)alloc((size_t)NE * 4);
    float* val8  = (float*)alloc((size_t)8 * B_ * 4);
    int*   idx8  = (int*)alloc((size_t)8 * B_ * 4);
    int*   idxf  = (int*)alloc((size_t)B_ * 4);
    float* part  = (float*)alloc(64 * 4);

    // casts / transposes (weights -> [N][K] bf16)
    cast_bf16<<<(size_t)B_ * DIN / 1024, 256, 0, stream>>>(x, x_bf);
    cast_bf16<<<(size_t)NE * DL / 1024, 256, 0, stream>>>(cbk, cb_bf);
    transpose_cast<<<dim3(DH / 32, DIN / 32), 256, 0, stream>>>(ew1, w1t, DIN, DH);
    transpose_cast<<<dim3(DL / 32, DH / 32), 256, 0, stream>>>(ew2, w2t, DH, DL);
    transpose_cast<<<dim3(DH / 32, DL / 32), 256, 0, stream>>>(dw1, wd1t, DL, DH);
    transpose_cast<<<dim3(DIN / 32, DH / 32), 256, 0, stream>>>(dw2, wd2t, DH, DIN);
    cn2_kernel<<<NE / 4, 256, 0, stream>>>(cbk, cn2);

    // encoder
    gemm_big_bf16<1><<<(B_ / 256) * (DH / 128), 512, 0, stream>>>(
        x_bf, w1t, eb1, h_bf, B_, DH, DIN);
    gemm_bt_bf16<0><<<(B_ / 128) * (DL / 128), 256, 0, stream>>>(
        h_bf, w2t, eb2, z_bf, B_, DL, DH);

    // vector quantizer -> final index per row + loss
    vq_score2<<<512, 256, 0, stream>>>(z_bf, cb_bf, cn2, val8, idx8);
    vq_select2<<<B_ / 256, 256, 0, stream>>>(val8, idx8, z_bf, cbk, idxf, part);
    loss_finalize<<<1, 256, 0, stream>>>(part, out + (size_t)B_ * DIN);

    // decoder per CODE (8192 rows), then gather rows by index.
    // h_bf is dead after gemm2 -> reuse for Hcode [NE, DH].
    gemm_big_bf16<1><<<(NE / 256) * (DH / 128), 512, 0, stream>>>(
        cb_bf, wd1t, db1, h_bf, NE, DH, DL);
    gemm_big_bf16<2><<<(NE / 256) * (DIN / 128), 512, 0, stream>>>(
        h_bf, wd2t, db2, Xcode, NE, DIN, DH);
    gather_rows<<<B_ / 4, 256, 0, stream>>>(Xcode, idxf, out);
}